// Round 10
// baseline (1248.070 us; speedup 1.0000x reference)
//
#include <hip/hip_runtime.h>
#include <hip/hip_bf16.h>
#include <math.h>

// ---------------------------------------------------------------------------
// BashTransformer forward on MI355X. Round 18: gemm_bf16 gains a DBUF
// template path (r16's verified gemm64 schedule). G5/G0 grids are only 384
// blocks = 1.5 blocks/CU (r16 premise of ~4/CU was wrong) -> their per-K
// vmcnt(0) drains were fully exposed; DBUF=1 hides them. G4 (768 blocks =
// 3/CU) keeps DBUF=0 per m132 (don't trade co-residency for 64KB LDS).
// r17 T1 XCD swizzle + swizzled LDS retained everywhere. delta_scan r13.
// ---------------------------------------------------------------------------

#define LSEQ 1024
#define BATCH 4
#define HIDDEN 512
#define NHEAD 8
#define HDIM 64
#define SHEAD 8
#define SDHD 32
#define SDIMM 256
#define FFND 1536
#define VOCN 63
#define ATTS 72   // attn LDS row stride (elems): 144B = 16B-aligned, 2-way banks

typedef __bf16 bf16;
typedef __attribute__((ext_vector_type(8))) __bf16 bf16x8;
typedef __attribute__((ext_vector_type(4))) float floatx4;

union BF4 { bf16 h[4]; short4 p; };

__device__ __forceinline__ void gload16(const void* g, const void* l) {
    __builtin_amdgcn_global_load_lds(
        (__attribute__((address_space(1))) unsigned int*)(uintptr_t)g,
        (__attribute__((address_space(3))) unsigned int*)(unsigned int)(uintptr_t)l,
        16, 0, 0);
}

// sum over aligned groups of 8 lanes, pure DPP (VALU pipe, no LDS counters)
__device__ __forceinline__ float sum8(float x) {
    x += __int_as_float(__builtin_amdgcn_mov_dpp(__float_as_int(x), 0xB1, 0xF, 0xF, true));
    x += __int_as_float(__builtin_amdgcn_mov_dpp(__float_as_int(x), 0x4E, 0xF, 0xF, true));
    x += __int_as_float(__builtin_amdgcn_mov_dpp(__float_as_int(x), 0x141, 0xF, 0xF, true));
    return x;
}

// T1: bijective XCD-aware remap (m204). Blocks with equal orig%8 (same XCD
// under round-robin dispatch) get a CONTIGUOUS range of logical ids, so
// x-major neighbors sharing operand panels stay on one XCD's L2.
__device__ __forceinline__ int xcd_swz(int lin, int nwg) {
    int q = nwg >> 3, r = nwg & 7;
    int xcd = lin & 7, sub = lin >> 3;
    return (xcd < r ? xcd * (q + 1) : r * (q + 1) + (xcd - r) * q) + sub;
}

// ------------------------------- rope tables -------------------------------
__global__ void rope_tables_k(float* __restrict__ cosT, float* __restrict__ sinT) {
    int idx = blockIdx.x * 256 + threadIdx.x;   // 32768 = 1024*32
    int l = idx >> 5, d = idx & 31;
    double ang = (double)l * pow(500000.0, -(double)(2 * d) / 64.0);
    cosT[idx] = (float)cos(ang);
    sinT[idx] = (float)sin(ang);
}

// ------------------------------- embedding ---------------------------------
__global__ void embed_k(const int* __restrict__ ids, const float* __restrict__ emb,
                        float* __restrict__ h) {
    int tok = blockIdx.x;
    int id = ids[tok];
    ((float4*)(h + (size_t)tok * HIDDEN))[threadIdx.x] =
        ((const float4*)(emb + (size_t)id * HIDDEN))[threadIdx.x];
}

// ------------------------------- casts -------------------------------------
__global__ void cast_plain(const float* __restrict__ s, bf16* __restrict__ d, int n4) {
    int i = blockIdx.x * 256 + threadIdx.x;
    if (i >= n4) return;
    float4 v = ((const float4*)s)[i];
    BF4 u;
    u.h[0] = (bf16)v.x; u.h[1] = (bf16)v.y; u.h[2] = (bf16)v.z; u.h[3] = (bf16)v.w;
    ((short4*)d)[i] = u.p;
}

// six 256x512 f32 matrices -> one fused 1536x512 bf16 (order s0..s5)
__global__ void cast6(const float* s0, const float* s1, const float* s2,
                      const float* s3, const float* s4, const float* s5,
                      bf16* __restrict__ d) {
    int i = blockIdx.x * 256 + threadIdx.x;      // 196608 short4s
    if (i >= 196608) return;
    int which = i >> 15, loc = i & 32767;
    const float* s = which == 0 ? s0 : which == 1 ? s1 : which == 2 ? s2
                    : which == 3 ? s3 : which == 4 ? s4 : s5;
    float4 v = ((const float4*)s)[loc];
    BF4 u;
    u.h[0] = (bf16)v.x; u.h[1] = (bf16)v.y; u.h[2] = (bf16)v.z; u.h[3] = (bf16)v.w;
    ((short4*)d)[i] = u.p;
}

// wq/wk/wv (6,512,512) each -> fused (6,1536,512) rows [layer*1536+which*512+r]
__global__ void cast_qkv(const float* __restrict__ q, const float* __restrict__ k,
                         const float* __restrict__ v, bf16* __restrict__ d) {
    int idx = blockIdx.x * 256 + threadIdx.x;    // 3*393216
    if (idx >= 1179648) return;
    int which = idx / 393216;
    int rem = idx - which * 393216;
    const float* s = which == 0 ? q : which == 1 ? k : v;
    int layer = rem >> 16, rr = rem & 65535;     // 512*128 per layer
    int r = rr >> 7, c4 = rr & 127;
    float4 x = ((const float4*)s)[rem];
    BF4 u;
    u.h[0] = (bf16)x.x; u.h[1] = (bf16)x.y; u.h[2] = (bf16)x.z; u.h[3] = (bf16)x.w;
    ((short4*)d)[((size_t)layer * 1536 + which * 512 + r) * 128 + c4] = u.p;
}

// w_gate/w_up (6,1536,512) -> interleaved (6,3072,512) rows [layer*3072+2r+which]
__global__ void cast_gu(const float* __restrict__ g, const float* __restrict__ uu,
                        bf16* __restrict__ d) {
    int idx = blockIdx.x * 256 + threadIdx.x;    // 2*1179648
    if (idx >= 2359296) return;
    int which = idx / 1179648;
    int rem = idx - which * 1179648;
    const float* s = which == 0 ? g : uu;
    int layer = rem / 196608, rr = rem - layer * 196608;  // 1536*128
    int r = rr >> 7, c4 = rr & 127;
    float4 x = ((const float4*)s)[rem];
    BF4 u;
    u.h[0] = (bf16)x.x; u.h[1] = (bf16)x.y; u.h[2] = (bf16)x.z; u.h[3] = (bf16)x.w;
    ((short4*)d)[((size_t)layer * 3072 + r * 2 + which) * 128 + c4] = u.p;
}

__global__ void cast_embed_pad(const float* __restrict__ s, bf16* __restrict__ d) {
    int i = blockIdx.x * 256 + threadIdx.x;   // 128*128 = 16384 short4s
    int row = i >> 7, c4 = i & 127;
    BF4 u;
    if (row < VOCN) {
        float4 v = ((const float4*)s)[row * 128 + c4];
        u.h[0] = (bf16)v.x; u.h[1] = (bf16)v.y; u.h[2] = (bf16)v.z; u.h[3] = (bf16)v.w;
    } else {
        u.h[0] = (bf16)0.f; u.h[1] = (bf16)0.f; u.h[2] = (bf16)0.f; u.h[3] = (bf16)0.f;
    }
    ((short4*)d)[i] = u.p;
}

// ------------------------------- rmsnorm -> bf16 ---------------------------
__global__ void rmsnorm512(const float* __restrict__ in, const float* __restrict__ w,
                           bf16* __restrict__ out) {
    int row = blockIdx.x, t = threadIdx.x;     // 128 threads
    float4 x = ((const float4*)(in + (size_t)row * 512))[t];
    float s = x.x * x.x + x.y * x.y + x.z * x.z + x.w * x.w;
    for (int m = 1; m < 64; m <<= 1) s += __shfl_xor(s, m);
    __shared__ float red[2];
    if ((t & 63) == 0) red[t >> 6] = s;
    __syncthreads();
    float tot = red[0] + red[1];
    float r = rsqrtf(tot * (1.f / 512.f) + 1e-6f);
    float4 wv = ((const float4*)w)[t];
    BF4 u;
    u.h[0] = (bf16)(x.x * r * wv.x); u.h[1] = (bf16)(x.y * r * wv.y);
    u.h[2] = (bf16)(x.z * r * wv.z); u.h[3] = (bf16)(x.w * r * wv.w);
    ((short4*)(out + (size_t)row * 512))[t] = u.p;
}

// ------------------------------- bf16 MFMA GEMM (128x128) ------------------
// C = A(bf16, MxK rm) @ B(bf16, NxK rm)^T. 128x128 tile, BK=64, 4 waves.
// LDS layout XOR-swizzled by 16B unit (pre-swizzled global source; see r14).
// T1 XCD-aware block swizzle (r17).
// DBUF=1: LDS double-buffer (stage k+1 before compute k) — for the 384-block
//   grids (G5/G0, 1.5 blocks/CU) whose barrier drains are otherwise exposed.
// DBUF=0: r17 single-buffer — for G4 (768 blocks = 3/CU cross-block overlap).
// MODE 0: C(f32)=v
// MODE 4: gate/up interleaved cols; Cb[row*Nreal+col/2]=bf16(silu(g)*u)
// MODE 5: fused QKV epilogue: RoPE(q,k)->Qb/Kb bf16 [bh][l][64], v->Vtb
//         [bh][d][l]. Requires N=1536 layout q|k|v and M = b-major tokens.
template <int MODE, int DBUF>
__global__ __launch_bounds__(256) void gemm_bf16(const bf16* __restrict__ A,
                                                 const bf16* __restrict__ B,
                                                 float* __restrict__ C,
                                                 bf16* __restrict__ Cb,
                                                 const float* __restrict__ cosT,
                                                 const float* __restrict__ sinT,
                                                 bf16* __restrict__ Qb,
                                                 bf16* __restrict__ Kb,
                                                 bf16* __restrict__ Vtb,
                                                 int M, int N, int K, int Nreal) {
    __shared__ bf16 As[(DBUF ? 2 : 1) * 128 * 64];
    __shared__ bf16 Bs[(DBUF ? 2 : 1) * 128 * 64];
    const int tid = threadIdx.x;
    const int wave = tid >> 6, lane = tid & 63;
    const int nx = gridDim.x;
    const int wg = xcd_swz(blockIdx.y * nx + blockIdx.x, nx * gridDim.y);
    const int row0 = (wg / nx) * 128, col0 = (wg % nx) * 128;
    floatx4 acc[4][4];
#pragma unroll
    for (int i = 0; i < 4; ++i)
#pragma unroll
        for (int j = 0; j < 4; ++j) acc[i][j] = (floatx4){0.f, 0.f, 0.f, 0.f};
    const int m0 = (wave & 1) * 64, n0 = (wave >> 1) * 64;
    const int sr = tid >> 3;                       // 32 rows per staging call
    const int ske = ((tid & 7) ^ (sr & 7)) * 8;    // pre-swizzled k offset (elems)
    const int ldst = wave * 1024;
    const int ua0 = (((lane >> 4) + 0) ^ (lane & 7)) * 16;   // kk=0 unit byte
    const int ua1 = (((lane >> 4) + 4) ^ (lane & 7)) * 16;   // kk=1 unit byte

    auto stage = [&](int k0, int buf) {
        char* AsB = (char*)As + (size_t)buf * 16384;
        char* BsB = (char*)Bs + (size_t)buf * 16384;
#pragma unroll
        for (int j = 0; j < 4; ++j) {
            gload16(A + (size_t)(row0 + j * 32 + sr) * K + ske + k0,
                    AsB + j * 4096 + ldst);
            gload16(B + (size_t)(col0 + j * 32 + sr) * K + ske + k0,
                    BsB + j * 4096 + ldst);
        }
    };
    auto compute = [&](int buf) {
        const char* AsB = (const char*)As + (size_t)buf * 16384;
        const char* BsB = (const char*)Bs + (size_t)buf * 16384;
#pragma unroll
        for (int kk = 0; kk < 2; ++kk) {
            const int uu = kk ? ua1 : ua0;
            bf16x8 af[4], bfr[4];
#pragma unroll
            for (int mi = 0; mi < 4; ++mi)
                af[mi] = *(const bf16x8*)(AsB + (m0 + mi * 16 + (lane & 15)) * 128 + uu);
#pragma unroll
            for (int ni = 0; ni < 4; ++ni)
                bfr[ni] = *(const bf16x8*)(BsB + (n0 + ni * 16 + (lane & 15)) * 128 + uu);
#pragma unroll
            for (int mi = 0; mi < 4; ++mi)
#pragma unroll
                for (int ni = 0; ni < 4; ++ni)
                    acc[mi][ni] = __builtin_amdgcn_mfma_f32_16x16x32_bf16(af[mi], bfr[ni], acc[mi][ni], 0, 0, 0);
        }
    };

    const int nk = K >> 6;
    if constexpr (DBUF) {
        stage(0, 0);
        __syncthreads();
        int cur = 0;
        for (int t = 0; t < nk; ++t, cur ^= 1) {
            if (t + 1 < nk) stage((t + 1) * 64, cur ^ 1);
            compute(cur);
            __syncthreads();
        }
    } else {
        for (int t = 0; t < nk; ++t) {
            stage(t * 64, 0);
            __syncthreads();
            compute(0);
            __syncthreads();
        }
    }

    const int cr = (lane >> 4) * 4;
    const int cc = lane & 15;
    if (MODE == 5) {
        // wave-uniform 64-col span: segment + head fixed per wave
        int segbase = col0 + n0;
        int seg = segbase >> 9;           // 0=q 1=k 2=v
        int head = (segbase >> 6) & 7;
#pragma unroll
        for (int mi = 0; mi < 4; ++mi) {
#pragma unroll
            for (int r = 0; r < 4; ++r) {
                int row = row0 + m0 + mi * 16 + cr + r;
                int b = row >> 10, l = row & 1023;
                size_t bh = (size_t)(b * 8 + head);
                float x0 = acc[mi][0][r], x1 = acc[mi][1][r];
                float x2 = acc[mi][2][r], x3 = acc[mi][3][r];
                if (seg < 2) {
                    float c0 = cosT[l * 32 + cc], c1 = cosT[l * 32 + 16 + cc];
                    float s0 = sinT[l * 32 + cc], s1 = sinT[l * 32 + 16 + cc];
                    bf16* dst = (seg == 0 ? Qb : Kb) + bh * 65536 + l * 64;
                    dst[cc]      = (bf16)(x0 * c0 - x2 * s0);
                    dst[16 + cc] = (bf16)(x1 * c1 - x3 * s1);
                    dst[32 + cc] = (bf16)(x2 * c0 + x0 * s0);
                    dst[48 + cc] = (bf16)(x3 * c1 + x1 * s1);
                } else {
                    bf16* dst = Vtb + bh * 65536 + l;
                    dst[(size_t)(cc) * 1024]      = (bf16)x0;
                    dst[(size_t)(16 + cc) * 1024] = (bf16)x1;
                    dst[(size_t)(32 + cc) * 1024] = (bf16)x2;
                    dst[(size_t)(48 + cc) * 1024] = (bf16)x3;
                }
            }
        }
        return;
    }
#pragma unroll
    for (int mi = 0; mi < 4; ++mi) {
#pragma unroll
        for (int ni = 0; ni < 4; ++ni) {
#pragma unroll
            for (int r = 0; r < 4; ++r) {
                int row = row0 + m0 + mi * 16 + cr + r;
                int col = col0 + n0 + ni * 16 + cc;
                float v = acc[mi][ni][r];
                if (MODE == 4) {
                    float o = __shfl_xor(v, 1);
                    if (!(lane & 1)) {
                        float sg = v / (1.f + __expf(-v));
                        Cb[(size_t)row * Nreal + (col >> 1)] = (bf16)(sg * o);
                    }
                } else if (col < Nreal) {
                    size_t off = (size_t)row * Nreal + col;
                    if (MODE == 0) C[off] = v;
                }
            }
        }
    }
}

// ---------------------- 64x128-tile GEMM (accumulate) ----------------------
// Tile M=64, N=128, 4 waves each 32x64, BK=64, swizzled LDS (round 14).
// Round 16: LDS double-buffered (1 block/CU grids -> drains were exposed).
// Round 17: T1 XCD-aware block swizzle.
// MODE 0: C=v  MODE 1: C+=v
template <int MODE>
__global__ __launch_bounds__(256) void gemm64_bf16(const bf16* __restrict__ A,
                                                   const bf16* __restrict__ B,
                                                   float* __restrict__ C,
                                                   int M, int N, int K, int Nreal) {
    __shared__ bf16 As[2][64 * 64];
    __shared__ bf16 Bs[2][128 * 64];
    const int tid = threadIdx.x;
    const int wave = tid >> 6, lane = tid & 63;
    const int nx = gridDim.x;
    const int wg = xcd_swz(blockIdx.y * nx + blockIdx.x, nx * gridDim.y);
    const int row0 = (wg / nx) * 64, col0 = (wg % nx) * 128;
    floatx4 acc[2][4];
#pragma unroll
    for (int i = 0; i < 2; ++i)
#pragma unroll
        for (int j = 0; j < 4; ++j) acc[i][j] = (floatx4){0.f, 0.f, 0.f, 0.f};
    const int m0 = (wave & 1) * 32, n0 = (wave >> 1) * 64;
    const int sr = tid >> 3;
    const int ske = ((tid & 7) ^ (sr & 7)) * 8;
    const int ldst = wave * 1024;
    const int ua0 = (((lane >> 4) + 0) ^ (lane & 7)) * 16;
    const int ua1 = (((lane >> 4) + 4) ^ (lane & 7)) * 16;

    auto stage = [&](int k0, int buf) {
        char* AsB = (char*)As[buf];
        char* BsB = (char*)Bs[buf];
#pragma unroll
        for (int j = 0; j < 2; ++j)
            gload16(A + (size_t)(row0 + j * 32 + sr) * K + ske + k0,
                    AsB + j * 4096 + ldst);
#pragma unroll
        for (int j = 0; j < 4; ++j)
            gload16(B + (size_t)(col0 + j * 32 + sr) * K + ske + k0,
                    BsB + j * 4096 + ldst);
    };

    const int nk = K >> 6;
    stage(0, 0);
    __syncthreads();
    int cur = 0;
    for (int t = 0; t < nk; ++t, cur ^= 1) {
        if (t + 1 < nk) stage((t + 1) * 64, cur ^ 1);
        const char* AsB = (const char*)As[cur];
        const char* BsB = (const char*)Bs[cur];
#pragma unroll
        for (int kk = 0; kk < 2; ++kk) {
            const int uu = kk ? ua1 : ua0;
            bf16x8 af[2], bfr[4];
#pragma unroll
            for (int mi = 0; mi < 2; ++mi)
                af[mi] = *(const bf16x8*)(AsB + (m0 + mi * 16 + (lane & 15)) * 128 + uu);
#pragma unroll
            for (int ni = 0; ni < 4; ++ni)
                bfr[ni] = *(const bf16x8*)(BsB + (n0 + ni * 16 + (lane & 15)) * 128 + uu);
#pragma unroll
            for (int mi = 0; mi < 2; ++mi)
#pragma unroll
                for (int ni = 0; ni < 4; ++ni)
                    acc[mi][ni] = __builtin_amdgcn_mfma_f32_16x16x32_bf16(af[mi], bfr[ni], acc[mi][ni], 0, 0, 0);
        }
        __syncthreads();
    }
    const int cr = (lane >> 4) * 4;
    const int cc = lane & 15;
#pragma unroll
    for (int mi = 0; mi < 2; ++mi) {
#pragma unroll
        for (int ni = 0; ni < 4; ++ni) {
#pragma unroll
            for (int r = 0; r < 4; ++r) {
                int row = row0 + m0 + mi * 16 + cr + r;
                int col = col0 + n0 + ni * 16 + cc;
                if (col < Nreal) {
                    size_t off = (size_t)row * Nreal + col;
                    float v = acc[mi][ni][r];
                    if (MODE == 0) C[off] = v;
                    else C[off] += v;
                }
            }
        }
    }
}

// ------------------------- MFMA flash attention ----------------------------
__global__ __launch_bounds__(256) void attn_mfma(const bf16* __restrict__ Qb,
                                                 const bf16* __restrict__ Kb,
                                                 const bf16* __restrict__ Vtb,
                                                 bf16* __restrict__ O) {
    int qt = blockIdx.x, hh = blockIdx.y, b = blockIdx.z;
    int bh = b * 8 + hh;
    int q0 = qt * 64;
    const bf16* Qg = Qb + ((size_t)bh * 1024 + q0) * 64;
    const bf16* Kg = Kb + (size_t)bh * 1024 * 64;
    const bf16* Vg = Vtb + (size_t)bh * 64 * 1024;   // [64 d][1024 l]
    __shared__ bf16 Qs[64 * ATTS];
    __shared__ bf16 Ks[64 * ATTS];
    __shared__ bf16 Vs[64 * ATTS];
    __shared__ bf16 Ps[64 * ATTS];
    int tid = threadIdx.x, wave = tid >> 6, lane = tid & 63;
    int lr = lane & 15, quad = lane >> 4;

#pragma unroll
    for (int it = 0; it < 2; ++it) {
        int cidx = tid + it * 256;
        int row = cidx >> 3, ch = cidx & 7;
        *(bf16x8*)(Qs + row * ATTS + ch * 8) = *(const bf16x8*)(Qg + row * 64 + ch * 8);
    }
    float mrow[4], lrow[4];
    floatx4 Oacc[4];
#pragma unroll
    for (int r = 0; r < 4; ++r) { mrow[r] = -1e30f; lrow[r] = 0.f; }
#pragma unroll
    for (int d0 = 0; d0 < 4; ++d0) Oacc[d0] = (floatx4){0.f, 0.f, 0.f, 0.f};

    int ntiles = qt + 1;
    for (int t = 0; t < ntiles; ++t) {
        int kv0 = t * 64;
        __syncthreads();
#pragma unroll
        for (int it = 0; it < 2; ++it) {
            int cidx = tid + it * 256;
            int row = cidx >> 3, ch = cidx & 7;
            *(bf16x8*)(Ks + row * ATTS + ch * 8) =
                *(const bf16x8*)(Kg + (size_t)(kv0 + row) * 64 + ch * 8);
            *(bf16x8*)(Vs + row * ATTS + ch * 8) =
                *(const bf16x8*)(Vg + (size_t)row * 1024 + kv0 + ch * 8);
        }
        __syncthreads();
        bf16x8 aq[2];
#pragma unroll
        for (int kc = 0; kc < 2; ++kc)
            aq[kc] = *(const bf16x8*)(Qs + (wave * 16 + lr) * ATTS + kc * 32 + quad * 8);
        floatx4 sacc[4];
#pragma unroll
        for (int n0 = 0; n0 < 4; ++n0) {
            bf16x8 bk0 = *(const bf16x8*)(Ks + (n0 * 16 + lr) * ATTS + quad * 8);
            bf16x8 bk1 = *(const bf16x8*)(Ks + (n0 * 16 + lr) * ATTS + 32 + quad * 8);
            floatx4 z = (floatx4){0.f, 0.f, 0.f, 0.f};
            z = __builtin_amdgcn_mfma_f32_16x16x32_bf16(aq[0], bk0, z, 0, 0, 0);
            sacc[n0] = __builtin_amdgcn_mfma_f32_16x16x32_bf16(aq[1], bk1, z, 0, 0, 0);
        }
        float sv[4][4];
#pragma unroll
        for (int n0 = 0; n0 < 4; ++n0)
#pragma unroll
            for (int r = 0; r < 4; ++r) sv[n0][r] = sacc[n0][r] * 0.125f;
        if (t == ntiles - 1) {
#pragma unroll
            for (int n0 = 0; n0 < 4; ++n0)
#pragma unroll
                for (int r = 0; r < 4; ++r)
                    if (n0 * 16 + lr > wave * 16 + quad * 4 + r) sv[n0][r] = -1e30f;
        }
        float al[4];
#pragma unroll
        for (int r = 0; r < 4; ++r) {
            float tm = fmaxf(fmaxf(sv[0][r], sv[1][r]), fmaxf(sv[2][r], sv[3][r]));
            tm = fmaxf(tm, __shfl_xor(tm, 1));
            tm = fmaxf(tm, __shfl_xor(tm, 2));
            tm = fmaxf(tm, __shfl_xor(tm, 4));
            tm = fmaxf(tm, __shfl_xor(tm, 8));
            float mn = fmaxf(mrow[r], tm);
            al[r] = __expf(mrow[r] - mn);
            mrow[r] = mn;
        }
        float rs[4];
#pragma unroll
        for (int r = 0; r < 4; ++r) rs[r] = 0.f;
#pragma unroll
        for (int n0 = 0; n0 < 4; ++n0)
#pragma unroll
            for (int r = 0; r < 4; ++r) {
                float p = __expf(sv[n0][r] - mrow[r]);
                sv[n0][r] = p;
                rs[r] += p;
            }
#pragma unroll
        for (int r = 0; r < 4; ++r) {
            float t2 = rs[r];
            t2 += __shfl_xor(t2, 1);
            t2 += __shfl_xor(t2, 2);
            t2 += __shfl_xor(t2, 4);
            t2 += __shfl_xor(t2, 8);
            lrow[r] = lrow[r] * al[r] + t2;
        }
#pragma unroll
        for (int d0 = 0; d0 < 4; ++d0)
#pragma unroll
            for (int r = 0; r < 4; ++r) Oacc[d0][r] *= al[r];
#pragma unroll
        for (int n0 = 0; n0 < 4; ++n0)
#pragma unroll
            for (int r = 0; r < 4; ++r)
                Ps[(wave * 16 + quad * 4 + r) * ATTS + n0 * 16 + lr] = (bf16)sv[n0][r];
        bf16x8 ap[2];
#pragma unroll
        for (int kc = 0; kc < 2; ++kc)
            ap[kc] = *(const bf16x8*)(Ps + (wave * 16 + lr) * ATTS + kc * 32 + quad * 8);
#pragma unroll
        for (int d0 = 0; d0 < 4; ++d0) {
            bf16x8 bv0 = *(const bf16x8*)(Vs + (d0 * 16 + lr) * ATTS + quad * 8);
            bf16x8 bv1 = *(const bf16x8*)(Vs + (d0 * 16 + lr) * ATTS + 32 + quad * 8);
            Oacc[d0] = __builtin_amdgcn_mfma_f32_16x16x32_bf16(ap[0], bv0, Oacc[d0], 0, 0, 0);
            Oacc[d0] = __builtin_amdgcn_mfma_f32_16x16x32_bf16(ap[1], bv1, Oacc[d0], 0, 0, 0);
        }
    }
    float inv[4];
#pragma unroll
    for (int r = 0; r < 4; ++r) inv[r] = 1.f / lrow[r];
#pragma unroll
    for (int d0 = 0; d0 < 4; ++d0)
#pragma unroll
        for (int r = 0; r < 4; ++r) {
            int row = b * 1024 + q0 + wave * 16 + quad * 4 + r;
            int col = hh * 64 + d0 * 16 + lr;
            O[(size_t)row * 512 + col] = (bf16)(Oacc[d0][r] * inv[r]);
        }
}

// ------------------------------- delta scan --------------------------------
// Round 13 structure (verified, 95 us): 32 blocks x 512 threads. Waves 0-3
// (role 0) run the round-9 verified 2-token pair scan on chunk c; waves 4-7
// (role 1) stage chunk c+1 into the other LDS buffer. One barrier per chunk.
__global__ __launch_bounds__(512, 2) void delta_scan(
    const float* __restrict__ P, const float* __restrict__ S_in,
    const float* __restrict__ bbias, const float* __restrict__ abias,
    float* __restrict__ S_out, float* __restrict__ ctx) {
    int bh = blockIdx.x;
    int b = bh >> 3, hh = bh & 7;
    int tid = threadIdx.x;
    int role = tid >> 8;            // 0 = compute (waves 0-3), 1 = stage (4-7)
    int htid = tid & 255;
    int lane = htid & 63;
    int wv = htid >> 6;             // wave within role group
    int ri = wv * 8 + (lane >> 3);
    int c = lane & 7;
    bool cz = (c == 0);
    // double-buffered staging arrays (ks rows 64/65 = loadp pad)
    __shared__ __align__(16) float ks[2][66][36], qs[2][66][36], vs[2][66][36],
                                   bs[2][66][36], as_[2][66][36];
    __shared__ __align__(16) float cpair[2][33][4]; // [pair][c12,k1q1,k1q2,k2q2]
    __shared__ __align__(16) float cs[64][32];      // compute-only, single
    float4 S = *(const float4*)(S_in + ((size_t)bh * 32 + ri) * 32 + c * 4);

    int sc4 = htid & 7, sr0 = htid >> 3;   // staging map: token rows sr0, sr0+32
    float4 bB = *(const float4*)(bbias + hh * 32 + sc4 * 4);
    float4 bA = *(const float4*)(abias + hh * 32 + sc4 * 4);

    struct Pair {
        float4 k1, k2, q1, q2;
        float a1, a2, b1, b2, bv1, bv2;
        float c12, cq11, cq12, cq22;
    };

    auto dot4 = [](float4 s, float4 k) {
        return fmaf(s.w, k.w, fmaf(s.z, k.z, fmaf(s.y, k.y, s.x * k.x)));
    };

    // ---- stage one 64-token chunk into buffer `buf` (role-1 waves) ----
    auto stage_chunk = [&](int c0, int buf) {
        float (*ksH)[36] = ks[buf];
        float (*qsH)[36] = qs[buf];
        float (*vsH)[36] = vs[buf];
        float (*bsH)[36] = bs[buf];
        float (*asH)[36] = as_[buf];
        float (*cpH)[4]  = cpair[buf];
        const float* Pb = P + ((size_t)(b * 1024 + c0) * 1536) + hh * 32 + sc4 * 4;
#pragma unroll
        for (int it = 0; it < 2; ++it) {
            int tok = sr0 + it * 32;
            const float* pg = Pb + (size_t)tok * 1536;
            float4 kv = *(const float4*)(pg);
            float4 vv = *(const float4*)(pg + 256);
            float4 qv = *(const float4*)(pg + 512);
            float4 bv = *(const float4*)(pg + 768);
            float4 av = *(const float4*)(pg + 1024);
            float ss = kv.x * kv.x + kv.y * kv.y + kv.z * kv.z + kv.w * kv.w;
            ss = sum8(ss);
            float rn = 1.f / fmaxf(sqrtf(ss), 1e-12f);
            kv.x *= rn; kv.y *= rn; kv.z *= rn; kv.w *= rn;
            float4 bo, ao;
            bo.x = 1.f / (1.f + __expf(-(bv.x + bB.x)));
            bo.y = 1.f / (1.f + __expf(-(bv.y + bB.y)));
            bo.z = 1.f / (1.f + __expf(-(bv.z + bB.z)));
            bo.w = 1.f / (1.f + __expf(-(bv.w + bB.w)));
            ao.x = 1.f / (1.f + __expf(-(av.x + bA.x)));
            ao.y = 1.f / (1.f + __expf(-(av.y + bA.y)));
            ao.z = 1.f / (1.f + __expf(-(av.z + bA.z)));
            ao.w = 1.f / (1.f + __expf(-(av.w + bA.w)));
            float4 vo;
            vo.x = bo.x * vv.x; vo.y = bo.y * vv.y;
            vo.z = bo.z * vv.z; vo.w = bo.w * vv.w;
            // pair-shared dots: tokens 2j/2j+1 in adjacent 8-lane groups
            float kq = sum8(kv.x * qv.x + kv.y * qv.y + kv.z * qv.z + kv.w * qv.w);
            float4 ko, qo;
            ko.x = __shfl_xor(kv.x, 8); ko.y = __shfl_xor(kv.y, 8);
            ko.z = __shfl_xor(kv.z, 8); ko.w = __shfl_xor(kv.w, 8);
            qo.x = __shfl_xor(qv.x, 8); qo.y = __shfl_xor(qv.y, 8);
            qo.z = __shfl_xor(qv.z, 8); qo.w = __shfl_xor(qv.w, 8);
            float ckk = sum8(kv.x * ko.x + kv.y * ko.y + kv.z * ko.z + kv.w * ko.w);
            float ckq = sum8(kv.x * qo.x + kv.y * qo.y + kv.z * qo.z + kv.w * qo.w);
            *(float4*)&ksH[tok][sc4 * 4] = kv;
            *(float4*)&vsH[tok][sc4 * 4] = vo;
            *(float4*)&qsH[tok][sc4 * 4] = qv;
            *(float4*)&bsH[tok][sc4 * 4] = bo;
            *(float4*)&asH[tok][sc4 * 4] = ao;
            if ((htid & 7) == 0) {
                int pairi = tok >> 1;
                if (!(tok & 1)) {
                    cpH[pairi][0] = ckk;   // k1.k2
                    cpH[pairi][1] = kq;    // k1.q1
                    cpH[pairi][2] = ckq;   // k1.q2
                } else {
                    cpH[pairi][3] = kq;    // k2.q2
                }
            }
        }
    };

    // ---- scan one staged chunk from buffer `buf` (role-0 waves) ----
    auto scan_chunk = [&](int c0, int buf) {
        float (*ksH)[36] = ks[buf];
        float (*qsH)[36] = qs[buf];
        float (*vsH)[36] = vs[buf];
        float (*bsH)[36] = bs[buf];
        float (*asH)[36] = as_[buf];
        float (*cpH)[4]  = cpair[buf];
        auto loadp = [&](int t, Pair& Pr) {
            Pr.k1 = *(const float4*)&ksH[2 * t][c * 4];
            Pr.k2 = *(const float4*)&ksH[2 * t + 1][c * 4];
            Pr.q1 = *(const float4*)&qsH[2 * t][c * 4];
            Pr.q2 = *(const float4*)&qsH[2 * t + 1][c * 4];
            Pr.a1 = asH[2 * t][ri];  Pr.a2 = asH[2 * t + 1][ri];
            Pr.b1 = bsH[2 * t][ri];  Pr.b2 = bsH[2 * t + 1][ri];
            Pr.bv1 = vsH[2 * t][ri]; Pr.bv2 = vsH[2 * t + 1][ri];
            float4 cp = *(const float4*)&cpH[t][0];
            Pr.c12 = cp.x; Pr.cq11 = cp.y; Pr.cq12 = cp.z; Pr.cq22 = cp.w;
        };
        auto stepp = [&](const Pair& Pr, int t) {
            float d1  = sum8(dot4(S, Pr.k1));
            float d2  = sum8(dot4(S, Pr.k2));
            float dq1 = sum8(dot4(S, Pr.q1));
            float dq2 = sum8(dot4(S, Pr.q2));
            float u1 = fmaf(-(Pr.b1 * Pr.a1), d1, Pr.bv1);
            float au1 = Pr.a2 * u1;
            float A = Pr.a1 * Pr.a2;
            float pred2 = fmaf(au1, Pr.c12, A * d2);
            float u2 = fmaf(-Pr.b2, pred2, Pr.bv2);
            S.x = fmaf(u2, Pr.k2.x, fmaf(au1, Pr.k1.x, A * S.x));
            S.y = fmaf(u2, Pr.k2.y, fmaf(au1, Pr.k1.y, A * S.y));
            S.z = fmaf(u2, Pr.k2.z, fmaf(au1, Pr.k1.z, A * S.z));
            S.w = fmaf(u2, Pr.k2.w, fmaf(au1, Pr.k1.w, A * S.w));
            if (cz) {
                cs[2 * t][ri]     = fmaf(u1, Pr.cq11, Pr.a1 * dq1);
                cs[2 * t + 1][ri] = fmaf(u2, Pr.cq22, fmaf(au1, Pr.cq12, A * dq2));
            }
        };
        Pair PA, PB;
        loadp(0, PA);
        for (int t = 0; t < 32; t += 2) {
            loadp(t + 1, PB);
            stepp(PA, t);
            loadp(t + 2, PA);   // t==30 -> pair 32: pad rows 64/65, cpair[32]
            stepp(PB, t + 1);
        }
        // per-wave-own-rows ctx store: wave wv wrote cs[t][8wv..8wv+7]
        int gbase = b * 1024 + c0;
#pragma unroll
        for (int it = 0; it < 2; ++it) {
            int e = lane + it * 64;
            int t = e >> 1, j4 = wv * 2 + (e & 1);
            float4 val = *(const float4*)&cs[t][j4 * 4];
            *(float4*)(ctx + (size_t)(gbase + t) * 256 + hh * 32 + j4 * 4) = val;
        }
    };

    // ---- producer/consumer chunk pipeline ----
    if (role == 1) stage_chunk(0, 0);
    __syncthreads();
    for (int ch = 0; ch < 16; ++ch) {
        if (role == 1) {
            if (ch + 1 < 16) stage_chunk((ch + 1) * 64, (ch + 1) & 1);
        } else {
            scan_chunk(ch * 64, ch & 1);
        }
        __syncthreads();
    }
    if (role == 0)
        *(float4*)(S_out + ((size_t)bh * 32 + ri) * 32 + c * 4) = S;
}

// ------------- ctxbf = bf16(rmsnorm(ctx,nw)*silu(gate)), gate in P@1280 ----
__global__ void ctx_post(const float* __restrict__ ctx, const float* __restrict__ P,
                         const float* __restrict__ nw, bf16* __restrict__ out) {
    int row = blockIdx.x, t = threadIdx.x;  // 64 threads
    float4 x = ((const float4*)(ctx + (size_t)row * SDIMM))[t];
    float s = x.x * x.x + x.y * x.y + x.z * x.z + x.w * x.w;
    for (int m = 1; m < 64; m <<= 1) s += __shfl_xor(s, m);
    float r = rsqrtf(s * (1.f / 256.f) + 1e-6f);
    float4 n = ((const float4*)nw)[t];
    float4 g = ((const float4*)(P + (size_t)row * 1536 + 1280))[t];
    BF4 u;
    u.h[0] = (bf16)(x.x * r * n.x * (g.x / (1.f + __expf(-g.x))));
    u.h[1] = (bf16)(x.y * r * n.y * (g.y / (1.f + __expf(-g.y))));
    u.h[2] = (bf16)(x.z * r * n.z * (g.z / (1.f + __expf(-g.z))));
    u.h[3] = (bf16)(x.w * r * n.w * (g.w / (1.f + __expf(-g.w))));
    ((short4*)(out + (size_t)row * SDIMM))[t] = u.p;
}

// ---------------------------------------------------------------------------
extern "C" void kernel_launch(void* const* d_in, const int* in_sizes, int n_in,
                              void* d_out, int out_size, void* d_ws, size_t ws_size,
                              hipStream_t stream) {
    (void)in_sizes; (void)n_in; (void)out_size; (void)ws_size;
    const int* ids = (const int*)d_in[0];
    const float* state = (const float*)d_in[1];
    const float* embedw = (const float*)d_in[2];
    auto F = [&](int i) { return (const float*)d_in[i]; };

    char* wsb = (char*)d_ws;
    const size_t MB = 1048576;
    float* H    = (float*)(wsb);                 // 0-8 MB
    bf16*  XNbf = (bf16*)(wsb + 8 * MB);         // 8-12 (alias ctxf in delta)
    float* ctxf = (float*)(wsb + 8 * MB);
    bf16*  Hbf  = (bf16*)(wsb + 12 * MB);        // 12-16 (alias ctxb)
    bf16*  ctxb = (bf16*)(wsb + 12 * MB);
    float* P    = (float*)(wsb + 16 * MB);       // 16-40 (delta proj f32)
    bf16*  Obf  = (bf16*)(wsb + 40 * MB);        // 40-44 attn out
    bf16*  Qbuf = (bf16*)(wsb + 44 * MB);        // 44-48
    bf16*  Kbuf = (bf16*)(wsb + 48 * MB);        // 48-52
    bf16*  Vtb  = (bf16*)(wsb + 52 * MB);        // 52-56
    bf16*  A1b  = (bf16*)(wsb + 44 * MB);        // alias Q/K/Vt (dead after attn)
    float* cosT = (float*)(wsb + 58 * MB);
    float* sinT = cosT + 32768;
    float* Sbuf = sinT + 32768;
    char*  wbase = wsb + 59 * MB;
    bf16* wqkv  = (bf16*)(wbase);                        // 6x1536x512
    bf16* wob   = (bf16*)(wbase + 9437184);              // 6x512x512
    bf16* wgu   = (bf16*)(wbase + 12582912);             // 6x3072x512 interleaved
    bf16* wdnb  = (bf16*)(wbase + 31457280);             // 6x512x1536
    bf16* wdR   = (bf16*)(wbase + 40894464);             // 1536x512
    bf16* woutR = (bf16*)(wbase + 42467328);             // 512x256
    bf16* wdW   = (bf16*)(wbase + 42729472);             // 1536x512
    bf16* woutW = (bf16*)(wbase + 44302336);             // 512x256
    bf16* embp  = (bf16*)(wbase + 44564480);             // 128x512 padded

    float* out = (float*)d_out;
    float* logits = out;
    float* Sout = out + 4096 * VOCN;

    // 128x128-tile launches
    auto G0 = [&](const bf16* A, const bf16* B, float* C, int M, int N, int K, int Nreal) {
        gemm_bf16<0, 1><<<dim3(N / 128, M / 128), 256, 0, stream>>>(
            A, B, C, nullptr, nullptr, nullptr, nullptr, nullptr, nullptr, M, N, K, Nreal);
    };
    auto G4 = [&](const bf16* A, const bf16* B, bf16* Cb, int M, int N, int K, int Nreal) {
        gemm_bf16<4, 0><<<dim3(N / 128, M / 128), 256, 0, stream>>>(
            A, B, nullptr, Cb, nullptr, nullptr, nullptr, nullptr, nullptr, M, N, K, Nreal);
    };
    auto G5 = [&](const bf16* A, const bf16* B, int M, int N, int K) {
        gemm_bf16<5, 1><<<dim3(N / 128, M / 128), 256, 0, stream>>>(
            A, B, nullptr, nullptr, cosT, sinT, Qbuf, Kbuf, Vtb, M, N, K, N);
    };
    // 64x128-tile accumulate
    auto G1s = [&](const bf16* A, const bf16* B, float* C, int M, int N, int K) {
        gemm64_bf16<1><<<dim3(N / 128, M / 64), 256, 0, stream>>>(A, B, C, M, N, K, N);
    };
    auto G0s = [&](const bf16* A, const bf16* B, float* C, int M, int N, int K, int Nreal) {
        gemm64_bf16<0><<<dim3(N / 128, M / 64), 256, 0, stream>>>(A, B, C, M, N, K, Nreal);
    };
    auto CP = [&](const float* s, bf16* d, int n4) {
        cast_plain<<<(n4 + 255) / 256, 256, 0, stream>>>(s, d, n4);
    };

    // ---- weight casts ----
    cast_qkv<<<4608, 256, 0, stream>>>(F(24), F(25), F(26), wqkv);
    CP(F(27), wob, 393216);
    cast_gu<<<9216, 256, 0, stream>>>(F(29), F(30), wgu);
    CP(F(31), wdnb, 1179648);
    cast6<<<768, 256, 0, stream>>>(F(3), F(4), F(5), F(6), F(8), F(12), wdR);
    CP(F(10), woutR, 32768);
    cast6<<<768, 256, 0, stream>>>(F(13), F(14), F(15), F(16), F(18), F(22), wdW);
    CP(F(20), woutW, 32768);
    cast_embed_pad<<<64, 256, 0, stream>>>(embedw, embp);

    rope_tables_k<<<128, 256, 0, stream>>>(cosT, sinT);
    embed_k<<<4096, 128, 0, stream>>>(ids, embedw, H);

    // ---- delta read ----
    CP(H, Hbf, 524288);
    G0(Hbf, wdR, P, 4096, 1536, 512, 1536);
    delta_scan<<<32, 512, 0, stream>>>(P, state, F(7), F(9), Sbuf, ctxf);
    ctx_post<<<4096, 64, 0, stream>>>(ctxf, P, F(11), ctxb);
    G1s(ctxb, woutR, H, 4096, 512, 256);

    for (int i = 0; i < 6; ++i) {
        rmsnorm512<<<4096, 128, 0, stream>>>(H, F(23) + (size_t)i * 512, XNbf);
        G5(XNbf, wqkv + (size_t)i * 1536 * 512, 4096, 1536, 512);
        attn_mfma<<<dim3(16, 8, 4), 256, 0, stream>>>(Qbuf, Kbuf, Vtb, Obf);
        G1s(Obf, wob + (size_t)i * 512 * 512, H, 4096, 512, 512);
        rmsnorm512<<<4096, 128, 0, stream>>>(H, F(28) + (size_t)i * 512, XNbf);
        G4(XNbf, wgu + (size_t)i * 3072 * 512, A1b, 4096, 3072, 512, 1536);
        G1s(A1b, wdnb + (size_t)i * 512 * 1536, H, 4096, 512, 1536);
    }

    // ---- delta write ----
    CP(H, Hbf, 524288);
    G0(Hbf, wdW, P, 4096, 1536, 512, 1536);
    delta_scan<<<32, 512, 0, stream>>>(P, Sbuf, F(17), F(19), Sout, ctxf);
    ctx_post<<<4096, 64, 0, stream>>>(ctxf, P, F(21), ctxb);
    G1s(ctxb, woutW, H, 4096, 512, 256);

    rmsnorm512<<<4096, 128, 0, stream>>>(H, F(32), XNbf);
    G0s(XNbf, embp, logits, 4096, 128, 512, VOCN);
}

// Round 11
// 1188.078 us; speedup vs baseline: 1.0505x; 1.0505x over previous
//
#include <hip/hip_runtime.h>
#include <hip/hip_bf16.h>
#include <math.h>

// ---------------------------------------------------------------------------
// BashTransformer forward on MI355X. Round 19: revert r18's gemm_bf16 DBUF
// (neutral-to-negative -> G5/G0 are epilogue-bound, not drain-bound). Fix
// the actual cost: MODE5 V-segment store was a 2B/2048B-stride scatter (64
// cache lines per store instr). Now: per-wave 8KB LDS transpose tile
// (XOR-swizzled 16B units) after the K-loop -> coalesced 16B Vtb stores
// (one full 128B line per 8-lane group). Bit-exact. r17 T1 XCD swizzle +
// swizzled LDS + gemm64 dbuf retained; delta_scan r13 (95us) unchanged.
// ---------------------------------------------------------------------------

#define LSEQ 1024
#define BATCH 4
#define HIDDEN 512
#define NHEAD 8
#define HDIM 64
#define SHEAD 8
#define SDHD 32
#define SDIMM 256
#define FFND 1536
#define VOCN 63
#define ATTS 72   // attn LDS row stride (elems): 144B = 16B-aligned, 2-way banks

typedef __bf16 bf16;
typedef __attribute__((ext_vector_type(8))) __bf16 bf16x8;
typedef __attribute__((ext_vector_type(4))) float floatx4;

union BF4 { bf16 h[4]; short4 p; };

__device__ __forceinline__ void gload16(const void* g, const void* l) {
    __builtin_amdgcn_global_load_lds(
        (__attribute__((address_space(1))) unsigned int*)(uintptr_t)g,
        (__attribute__((address_space(3))) unsigned int*)(unsigned int)(uintptr_t)l,
        16, 0, 0);
}

// sum over aligned groups of 8 lanes, pure DPP (VALU pipe, no LDS counters)
__device__ __forceinline__ float sum8(float x) {
    x += __int_as_float(__builtin_amdgcn_mov_dpp(__float_as_int(x), 0xB1, 0xF, 0xF, true));
    x += __int_as_float(__builtin_amdgcn_mov_dpp(__float_as_int(x), 0x4E, 0xF, 0xF, true));
    x += __int_as_float(__builtin_amdgcn_mov_dpp(__float_as_int(x), 0x141, 0xF, 0xF, true));
    return x;
}

// T1: bijective XCD-aware remap (m204). Blocks with equal orig%8 (same XCD
// under round-robin dispatch) get a CONTIGUOUS range of logical ids, so
// x-major neighbors sharing operand panels stay on one XCD's L2.
__device__ __forceinline__ int xcd_swz(int lin, int nwg) {
    int q = nwg >> 3, r = nwg & 7;
    int xcd = lin & 7, sub = lin >> 3;
    return (xcd < r ? xcd * (q + 1) : r * (q + 1) + (xcd - r) * q) + sub;
}

// ------------------------------- rope tables -------------------------------
__global__ void rope_tables_k(float* __restrict__ cosT, float* __restrict__ sinT) {
    int idx = blockIdx.x * 256 + threadIdx.x;   // 32768 = 1024*32
    int l = idx >> 5, d = idx & 31;
    double ang = (double)l * pow(500000.0, -(double)(2 * d) / 64.0);
    cosT[idx] = (float)cos(ang);
    sinT[idx] = (float)sin(ang);
}

// ------------------------------- embedding ---------------------------------
__global__ void embed_k(const int* __restrict__ ids, const float* __restrict__ emb,
                        float* __restrict__ h) {
    int tok = blockIdx.x;
    int id = ids[tok];
    ((float4*)(h + (size_t)tok * HIDDEN))[threadIdx.x] =
        ((const float4*)(emb + (size_t)id * HIDDEN))[threadIdx.x];
}

// ------------------------------- casts -------------------------------------
__global__ void cast_plain(const float* __restrict__ s, bf16* __restrict__ d, int n4) {
    int i = blockIdx.x * 256 + threadIdx.x;
    if (i >= n4) return;
    float4 v = ((const float4*)s)[i];
    BF4 u;
    u.h[0] = (bf16)v.x; u.h[1] = (bf16)v.y; u.h[2] = (bf16)v.z; u.h[3] = (bf16)v.w;
    ((short4*)d)[i] = u.p;
}

// six 256x512 f32 matrices -> one fused 1536x512 bf16 (order s0..s5)
__global__ void cast6(const float* s0, const float* s1, const float* s2,
                      const float* s3, const float* s4, const float* s5,
                      bf16* __restrict__ d) {
    int i = blockIdx.x * 256 + threadIdx.x;      // 196608 short4s
    if (i >= 196608) return;
    int which = i >> 15, loc = i & 32767;
    const float* s = which == 0 ? s0 : which == 1 ? s1 : which == 2 ? s2
                    : which == 3 ? s3 : which == 4 ? s4 : s5;
    float4 v = ((const float4*)s)[loc];
    BF4 u;
    u.h[0] = (bf16)v.x; u.h[1] = (bf16)v.y; u.h[2] = (bf16)v.z; u.h[3] = (bf16)v.w;
    ((short4*)d)[i] = u.p;
}

// wq/wk/wv (6,512,512) each -> fused (6,1536,512) rows [layer*1536+which*512+r]
__global__ void cast_qkv(const float* __restrict__ q, const float* __restrict__ k,
                         const float* __restrict__ v, bf16* __restrict__ d) {
    int idx = blockIdx.x * 256 + threadIdx.x;    // 3*393216
    if (idx >= 1179648) return;
    int which = idx / 393216;
    int rem = idx - which * 393216;
    const float* s = which == 0 ? q : which == 1 ? k : v;
    int layer = rem >> 16, rr = rem & 65535;     // 512*128 per layer
    int r = rr >> 7, c4 = rr & 127;
    float4 x = ((const float4*)s)[rem];
    BF4 u;
    u.h[0] = (bf16)x.x; u.h[1] = (bf16)x.y; u.h[2] = (bf16)x.z; u.h[3] = (bf16)x.w;
    ((short4*)d)[((size_t)layer * 1536 + which * 512 + r) * 128 + c4] = u.p;
}

// w_gate/w_up (6,1536,512) -> interleaved (6,3072,512) rows [layer*3072+2r+which]
__global__ void cast_gu(const float* __restrict__ g, const float* __restrict__ uu,
                        bf16* __restrict__ d) {
    int idx = blockIdx.x * 256 + threadIdx.x;    // 2*1179648
    if (idx >= 2359296) return;
    int which = idx / 1179648;
    int rem = idx - which * 1179648;
    const float* s = which == 0 ? g : uu;
    int layer = rem / 196608, rr = rem - layer * 196608;  // 1536*128
    int r = rr >> 7, c4 = rr & 127;
    float4 x = ((const float4*)s)[rem];
    BF4 u;
    u.h[0] = (bf16)x.x; u.h[1] = (bf16)x.y; u.h[2] = (bf16)x.z; u.h[3] = (bf16)x.w;
    ((short4*)d)[((size_t)layer * 3072 + r * 2 + which) * 128 + c4] = u.p;
}

__global__ void cast_embed_pad(const float* __restrict__ s, bf16* __restrict__ d) {
    int i = blockIdx.x * 256 + threadIdx.x;   // 128*128 = 16384 short4s
    int row = i >> 7, c4 = i & 127;
    BF4 u;
    if (row < VOCN) {
        float4 v = ((const float4*)s)[row * 128 + c4];
        u.h[0] = (bf16)v.x; u.h[1] = (bf16)v.y; u.h[2] = (bf16)v.z; u.h[3] = (bf16)v.w;
    } else {
        u.h[0] = (bf16)0.f; u.h[1] = (bf16)0.f; u.h[2] = (bf16)0.f; u.h[3] = (bf16)0.f;
    }
    ((short4*)d)[i] = u.p;
}

// ------------------------------- rmsnorm -> bf16 ---------------------------
__global__ void rmsnorm512(const float* __restrict__ in, const float* __restrict__ w,
                           bf16* __restrict__ out) {
    int row = blockIdx.x, t = threadIdx.x;     // 128 threads
    float4 x = ((const float4*)(in + (size_t)row * 512))[t];
    float s = x.x * x.x + x.y * x.y + x.z * x.z + x.w * x.w;
    for (int m = 1; m < 64; m <<= 1) s += __shfl_xor(s, m);
    __shared__ float red[2];
    if ((t & 63) == 0) red[t >> 6] = s;
    __syncthreads();
    float tot = red[0] + red[1];
    float r = rsqrtf(tot * (1.f / 512.f) + 1e-6f);
    float4 wv = ((const float4*)w)[t];
    BF4 u;
    u.h[0] = (bf16)(x.x * r * wv.x); u.h[1] = (bf16)(x.y * r * wv.y);
    u.h[2] = (bf16)(x.z * r * wv.z); u.h[3] = (bf16)(x.w * r * wv.w);
    ((short4*)(out + (size_t)row * 512))[t] = u.p;
}

// ------------------------------- bf16 MFMA GEMM (128x128) ------------------
// C = A(bf16, MxK rm) @ B(bf16, NxK rm)^T. 128x128 tile, BK=64, 4 waves.
// LDS layout XOR-swizzled by 16B unit (pre-swizzled global source; r14).
// T1 XCD-aware block swizzle (r17). Single-buffered (r18 DBUF was neutral:
// these launches are epilogue-bound, not drain-bound).
// MODE 0: C(f32)=v
// MODE 4: gate/up interleaved cols; Cb[row*Nreal+col/2]=bf16(silu(g)*u)
// MODE 5: fused QKV epilogue: RoPE(q,k)->Qb/Kb bf16 [bh][l][64]; V goes
//         through a per-wave LDS transpose tile (r19) and is stored to Vtb
//         [bh][d][l] with coalesced 16B lines instead of 2B/2KB scatters.
template <int MODE>
__global__ __launch_bounds__(256) void gemm_bf16(const bf16* __restrict__ A,
                                                 const bf16* __restrict__ B,
                                                 float* __restrict__ C,
                                                 bf16* __restrict__ Cb,
                                                 const float* __restrict__ cosT,
                                                 const float* __restrict__ sinT,
                                                 bf16* __restrict__ Qb,
                                                 bf16* __restrict__ Kb,
                                                 bf16* __restrict__ Vtb,
                                                 int M, int N, int K, int Nreal) {
    __shared__ bf16 As[128 * 64];
    __shared__ bf16 Bs[128 * 64];
    const int tid = threadIdx.x;
    const int wave = tid >> 6, lane = tid & 63;
    const int nx = gridDim.x;
    const int wg = xcd_swz(blockIdx.y * nx + blockIdx.x, nx * gridDim.y);
    const int row0 = (wg / nx) * 128, col0 = (wg % nx) * 128;
    floatx4 acc[4][4];
#pragma unroll
    for (int i = 0; i < 4; ++i)
#pragma unroll
        for (int j = 0; j < 4; ++j) acc[i][j] = (floatx4){0.f, 0.f, 0.f, 0.f};
    const int m0 = (wave & 1) * 64, n0 = (wave >> 1) * 64;
    const int sr = tid >> 3;                       // 32 rows per staging call
    const int ske = ((tid & 7) ^ (sr & 7)) * 8;    // pre-swizzled k offset (elems)
    char* AsB = (char*)As;
    char* BsB = (char*)Bs;
    const int ldst = wave * 1024;
    const int ua0 = (((lane >> 4) + 0) ^ (lane & 7)) * 16;   // kk=0 unit byte
    const int ua1 = (((lane >> 4) + 4) ^ (lane & 7)) * 16;   // kk=1 unit byte

    for (int k0 = 0; k0 < K; k0 += 64) {
#pragma unroll
        for (int j = 0; j < 4; ++j) {
            gload16(A + (size_t)(row0 + j * 32 + sr) * K + ske + k0,
                    AsB + j * 4096 + ldst);
            gload16(B + (size_t)(col0 + j * 32 + sr) * K + ske + k0,
                    BsB + j * 4096 + ldst);
        }
        __syncthreads();
#pragma unroll
        for (int kk = 0; kk < 2; ++kk) {
            const int uu = kk ? ua1 : ua0;
            bf16x8 af[4], bfr[4];
#pragma unroll
            for (int mi = 0; mi < 4; ++mi)
                af[mi] = *(const bf16x8*)(AsB + (m0 + mi * 16 + (lane & 15)) * 128 + uu);
#pragma unroll
            for (int ni = 0; ni < 4; ++ni)
                bfr[ni] = *(const bf16x8*)(BsB + (n0 + ni * 16 + (lane & 15)) * 128 + uu);
#pragma unroll
            for (int mi = 0; mi < 4; ++mi)
#pragma unroll
                for (int ni = 0; ni < 4; ++ni)
                    acc[mi][ni] = __builtin_amdgcn_mfma_f32_16x16x32_bf16(af[mi], bfr[ni], acc[mi][ni], 0, 0, 0);
        }
        __syncthreads();
    }
    const int cr = (lane >> 4) * 4;
    const int cc = lane & 15;
    if (MODE == 5) {
        // wave-uniform 64-col span: segment + head fixed per wave
        int segbase = col0 + n0;
        int seg = segbase >> 9;           // 0=q 1=k 2=v
        int head = (segbase >> 6) & 7;
        if (seg < 2) {
#pragma unroll
            for (int mi = 0; mi < 4; ++mi) {
#pragma unroll
                for (int r = 0; r < 4; ++r) {
                    int row = row0 + m0 + mi * 16 + cr + r;
                    int b = row >> 10, l = row & 1023;
                    size_t bh = (size_t)(b * 8 + head);
                    float x0 = acc[mi][0][r], x1 = acc[mi][1][r];
                    float x2 = acc[mi][2][r], x3 = acc[mi][3][r];
                    float c0 = cosT[l * 32 + cc], c1 = cosT[l * 32 + 16 + cc];
                    float s0 = sinT[l * 32 + cc], s1 = sinT[l * 32 + 16 + cc];
                    bf16* dst = (seg == 0 ? Qb : Kb) + bh * 65536 + l * 64;
                    dst[cc]      = (bf16)(x0 * c0 - x2 * s0);
                    dst[16 + cc] = (bf16)(x1 * c1 - x3 * s1);
                    dst[32 + cc] = (bf16)(x2 * c0 + x0 * s0);
                    dst[48 + cc] = (bf16)(x3 * c1 + x1 * s1);
                }
            }
        } else {
            // r19: per-wave LDS transpose tile (8KB, As/Bs dead after K-loop,
            // final barrier above already synced all waves). Tile layout
            // ldsT[d=0..63][l=0..63], row stride 128B, 16B units XOR-swizzled
            // by (d&7). Writes: 16x ds_write_b64 (<=4-way banks). Reads: each
            // 8-lane group consumes one full contiguous row -> conflict-free,
            // then coalesced 16B global stores (one 128B line per group).
            char* T = (wave < 2) ? ((char*)As + wave * 8192)
                                 : ((char*)Bs + (wave - 2) * 8192);
            int lb = row0 + m0;            // wave's token base (global row)
            int b = lb >> 10, l0 = lb & 1023;
            size_t bh = (size_t)(b * 8 + head);
            const int quad = lane >> 4;
            const int u = (quad >> 1);      // + mi*2 below
            const int h = (quad & 1) * 8;   // byte offset within unit
#pragma unroll
            for (int mi = 0; mi < 4; ++mi) {
#pragma unroll
                for (int ni = 0; ni < 4; ++ni) {
                    int d = ni * 16 + cc;
                    BF4 pk;
                    pk.h[0] = (bf16)acc[mi][ni][0];
                    pk.h[1] = (bf16)acc[mi][ni][1];
                    pk.h[2] = (bf16)acc[mi][ni][2];
                    pk.h[3] = (bf16)acc[mi][ni][3];
                    *(short4*)(T + d * 128 + ((mi * 2 + u) ^ (d & 7)) * 16 + h) = pk.p;
                }
            }
            int dl = lane >> 3, j = lane & 7;
#pragma unroll
            for (int i = 0; i < 8; ++i) {
                int d = i * 8 + dl;
                bf16x8 v = *(const bf16x8*)(T + d * 128 + ((j ^ dl) * 16));
                *(bf16x8*)(Vtb + bh * 65536 + (size_t)d * 1024 + l0 + j * 8) = v;
            }
        }
        return;
    }
#pragma unroll
    for (int mi = 0; mi < 4; ++mi) {
#pragma unroll
        for (int ni = 0; ni < 4; ++ni) {
#pragma unroll
            for (int r = 0; r < 4; ++r) {
                int row = row0 + m0 + mi * 16 + cr + r;
                int col = col0 + n0 + ni * 16 + cc;
                float v = acc[mi][ni][r];
                if (MODE == 4) {
                    float o = __shfl_xor(v, 1);
                    if (!(lane & 1)) {
                        float sg = v / (1.f + __expf(-v));
                        Cb[(size_t)row * Nreal + (col >> 1)] = (bf16)(sg * o);
                    }
                } else if (col < Nreal) {
                    size_t off = (size_t)row * Nreal + col;
                    if (MODE == 0) C[off] = v;
                }
            }
        }
    }
}

// ---------------------- 64x128-tile GEMM (accumulate) ----------------------
// Tile M=64, N=128, 4 waves each 32x64, BK=64, swizzled LDS (round 14).
// Round 16: LDS double-buffered (1 block/CU grids -> drains were exposed).
// Round 17: T1 XCD-aware block swizzle.
// MODE 0: C=v  MODE 1: C+=v
template <int MODE>
__global__ __launch_bounds__(256) void gemm64_bf16(const bf16* __restrict__ A,
                                                   const bf16* __restrict__ B,
                                                   float* __restrict__ C,
                                                   int M, int N, int K, int Nreal) {
    __shared__ bf16 As[2][64 * 64];
    __shared__ bf16 Bs[2][128 * 64];
    const int tid = threadIdx.x;
    const int wave = tid >> 6, lane = tid & 63;
    const int nx = gridDim.x;
    const int wg = xcd_swz(blockIdx.y * nx + blockIdx.x, nx * gridDim.y);
    const int row0 = (wg / nx) * 64, col0 = (wg % nx) * 128;
    floatx4 acc[2][4];
#pragma unroll
    for (int i = 0; i < 2; ++i)
#pragma unroll
        for (int j = 0; j < 4; ++j) acc[i][j] = (floatx4){0.f, 0.f, 0.f, 0.f};
    const int m0 = (wave & 1) * 32, n0 = (wave >> 1) * 64;
    const int sr = tid >> 3;
    const int ske = ((tid & 7) ^ (sr & 7)) * 8;
    const int ldst = wave * 1024;
    const int ua0 = (((lane >> 4) + 0) ^ (lane & 7)) * 16;
    const int ua1 = (((lane >> 4) + 4) ^ (lane & 7)) * 16;

    auto stage = [&](int k0, int buf) {
        char* AsB = (char*)As[buf];
        char* BsB = (char*)Bs[buf];
#pragma unroll
        for (int j = 0; j < 2; ++j)
            gload16(A + (size_t)(row0 + j * 32 + sr) * K + ske + k0,
                    AsB + j * 4096 + ldst);
#pragma unroll
        for (int j = 0; j < 4; ++j)
            gload16(B + (size_t)(col0 + j * 32 + sr) * K + ske + k0,
                    BsB + j * 4096 + ldst);
    };

    const int nk = K >> 6;
    stage(0, 0);
    __syncthreads();
    int cur = 0;
    for (int t = 0; t < nk; ++t, cur ^= 1) {
        if (t + 1 < nk) stage((t + 1) * 64, cur ^ 1);
        const char* AsB = (const char*)As[cur];
        const char* BsB = (const char*)Bs[cur];
#pragma unroll
        for (int kk = 0; kk < 2; ++kk) {
            const int uu = kk ? ua1 : ua0;
            bf16x8 af[2], bfr[4];
#pragma unroll
            for (int mi = 0; mi < 2; ++mi)
                af[mi] = *(const bf16x8*)(AsB + (m0 + mi * 16 + (lane & 15)) * 128 + uu);
#pragma unroll
            for (int ni = 0; ni < 4; ++ni)
                bfr[ni] = *(const bf16x8*)(BsB + (n0 + ni * 16 + (lane & 15)) * 128 + uu);
#pragma unroll
            for (int mi = 0; mi < 2; ++mi)
#pragma unroll
                for (int ni = 0; ni < 4; ++ni)
                    acc[mi][ni] = __builtin_amdgcn_mfma_f32_16x16x32_bf16(af[mi], bfr[ni], acc[mi][ni], 0, 0, 0);
        }
        __syncthreads();
    }
    const int cr = (lane >> 4) * 4;
    const int cc = lane & 15;
#pragma unroll
    for (int mi = 0; mi < 2; ++mi) {
#pragma unroll
        for (int ni = 0; ni < 4; ++ni) {
#pragma unroll
            for (int r = 0; r < 4; ++r) {
                int row = row0 + m0 + mi * 16 + cr + r;
                int col = col0 + n0 + ni * 16 + cc;
                if (col < Nreal) {
                    size_t off = (size_t)row * Nreal + col;
                    float v = acc[mi][ni][r];
                    if (MODE == 0) C[off] = v;
                    else C[off] += v;
                }
            }
        }
    }
}

// ------------------------- MFMA flash attention ----------------------------
__global__ __launch_bounds__(256) void attn_mfma(const bf16* __restrict__ Qb,
                                                 const bf16* __restrict__ Kb,
                                                 const bf16* __restrict__ Vtb,
                                                 bf16* __restrict__ O) {
    int qt = blockIdx.x, hh = blockIdx.y, b = blockIdx.z;
    int bh = b * 8 + hh;
    int q0 = qt * 64;
    const bf16* Qg = Qb + ((size_t)bh * 1024 + q0) * 64;
    const bf16* Kg = Kb + (size_t)bh * 1024 * 64;
    const bf16* Vg = Vtb + (size_t)bh * 64 * 1024;   // [64 d][1024 l]
    __shared__ bf16 Qs[64 * ATTS];
    __shared__ bf16 Ks[64 * ATTS];
    __shared__ bf16 Vs[64 * ATTS];
    __shared__ bf16 Ps[64 * ATTS];
    int tid = threadIdx.x, wave = tid >> 6, lane = tid & 63;
    int lr = lane & 15, quad = lane >> 4;

#pragma unroll
    for (int it = 0; it < 2; ++it) {
        int cidx = tid + it * 256;
        int row = cidx >> 3, ch = cidx & 7;
        *(bf16x8*)(Qs + row * ATTS + ch * 8) = *(const bf16x8*)(Qg + row * 64 + ch * 8);
    }
    float mrow[4], lrow[4];
    floatx4 Oacc[4];
#pragma unroll
    for (int r = 0; r < 4; ++r) { mrow[r] = -1e30f; lrow[r] = 0.f; }
#pragma unroll
    for (int d0 = 0; d0 < 4; ++d0) Oacc[d0] = (floatx4){0.f, 0.f, 0.f, 0.f};

    int ntiles = qt + 1;
    for (int t = 0; t < ntiles; ++t) {
        int kv0 = t * 64;
        __syncthreads();
#pragma unroll
        for (int it = 0; it < 2; ++it) {
            int cidx = tid + it * 256;
            int row = cidx >> 3, ch = cidx & 7;
            *(bf16x8*)(Ks + row * ATTS + ch * 8) =
                *(const bf16x8*)(Kg + (size_t)(kv0 + row) * 64 + ch * 8);
            *(bf16x8*)(Vs + row * ATTS + ch * 8) =
                *(const bf16x8*)(Vg + (size_t)row * 1024 + kv0 + ch * 8);
        }
        __syncthreads();
        bf16x8 aq[2];
#pragma unroll
        for (int kc = 0; kc < 2; ++kc)
            aq[kc] = *(const bf16x8*)(Qs + (wave * 16 + lr) * ATTS + kc * 32 + quad * 8);
        floatx4 sacc[4];
#pragma unroll
        for (int n0 = 0; n0 < 4; ++n0) {
            bf16x8 bk0 = *(const bf16x8*)(Ks + (n0 * 16 + lr) * ATTS + quad * 8);
            bf16x8 bk1 = *(const bf16x8*)(Ks + (n0 * 16 + lr) * ATTS + 32 + quad * 8);
            floatx4 z = (floatx4){0.f, 0.f, 0.f, 0.f};
            z = __builtin_amdgcn_mfma_f32_16x16x32_bf16(aq[0], bk0, z, 0, 0, 0);
            sacc[n0] = __builtin_amdgcn_mfma_f32_16x16x32_bf16(aq[1], bk1, z, 0, 0, 0);
        }
        float sv[4][4];
#pragma unroll
        for (int n0 = 0; n0 < 4; ++n0)
#pragma unroll
            for (int r = 0; r < 4; ++r) sv[n0][r] = sacc[n0][r] * 0.125f;
        if (t == ntiles - 1) {
#pragma unroll
            for (int n0 = 0; n0 < 4; ++n0)
#pragma unroll
                for (int r = 0; r < 4; ++r)
                    if (n0 * 16 + lr > wave * 16 + quad * 4 + r) sv[n0][r] = -1e30f;
        }
        float al[4];
#pragma unroll
        for (int r = 0; r < 4; ++r) {
            float tm = fmaxf(fmaxf(sv[0][r], sv[1][r]), fmaxf(sv[2][r], sv[3][r]));
            tm = fmaxf(tm, __shfl_xor(tm, 1));
            tm = fmaxf(tm, __shfl_xor(tm, 2));
            tm = fmaxf(tm, __shfl_xor(tm, 4));
            tm = fmaxf(tm, __shfl_xor(tm, 8));
            float mn = fmaxf(mrow[r], tm);
            al[r] = __expf(mrow[r] - mn);
            mrow[r] = mn;
        }
        float rs[4];
#pragma unroll
        for (int r = 0; r < 4; ++r) rs[r] = 0.f;
#pragma unroll
        for (int n0 = 0; n0 < 4; ++n0)
#pragma unroll
            for (int r = 0; r < 4; ++r) {
                float p = __expf(sv[n0][r] - mrow[r]);
                sv[n0][r] = p;
                rs[r] += p;
            }
#pragma unroll
        for (int r = 0; r < 4; ++r) {
            float t2 = rs[r];
            t2 += __shfl_xor(t2, 1);
            t2 += __shfl_xor(t2, 2);
            t2 += __shfl_xor(t2, 4);
            t2 += __shfl_xor(t2, 8);
            lrow[r] = lrow[r] * al[r] + t2;
        }
#pragma unroll
        for (int d0 = 0; d0 < 4; ++d0)
#pragma unroll
            for (int r = 0; r < 4; ++r) Oacc[d0][r] *= al[r];
#pragma unroll
        for (int n0 = 0; n0 < 4; ++n0)
#pragma unroll
            for (int r = 0; r < 4; ++r)
                Ps[(wave * 16 + quad * 4 + r) * ATTS + n0 * 16 + lr] = (bf16)sv[n0][r];
        bf16x8 ap[2];
#pragma unroll
        for (int kc = 0; kc < 2; ++kc)
            ap[kc] = *(const bf16x8*)(Ps + (wave * 16 + lr) * ATTS + kc * 32 + quad * 8);
#pragma unroll
        for (int d0 = 0; d0 < 4; ++d0) {
            bf16x8 bv0 = *(const bf16x8*)(Vs + (d0 * 16 + lr) * ATTS + quad * 8);
            bf16x8 bv1 = *(const bf16x8*)(Vs + (d0 * 16 + lr) * ATTS + 32 + quad * 8);
            Oacc[d0] = __builtin_amdgcn_mfma_f32_16x16x32_bf16(ap[0], bv0, Oacc[d0], 0, 0, 0);
            Oacc[d0] = __builtin_amdgcn_mfma_f32_16x16x32_bf16(ap[1], bv1, Oacc[d0], 0, 0, 0);
        }
    }
    float inv[4];
#pragma unroll
    for (int r = 0; r < 4; ++r) inv[r] = 1.f / lrow[r];
#pragma unroll
    for (int d0 = 0; d0 < 4; ++d0)
#pragma unroll
        for (int r = 0; r < 4; ++r) {
            int row = b * 1024 + q0 + wave * 16 + quad * 4 + r;
            int col = hh * 64 + d0 * 16 + lr;
            O[(size_t)row * 512 + col] = (bf16)(Oacc[d0][r] * inv[r]);
        }
}

// ------------------------------- delta scan --------------------------------
// Round 13 structure (verified, 95 us): 32 blocks x 512 threads. Waves 0-3
// (role 0) run the round-9 verified 2-token pair scan on chunk c; waves 4-7
// (role 1) stage chunk c+1 into the other LDS buffer. One barrier per chunk.
__global__ __launch_bounds__(512, 2) void delta_scan(
    const float* __restrict__ P, const float* __restrict__ S_in,
    const float* __restrict__ bbias, const float* __restrict__ abias,
    float* __restrict__ S_out, float* __restrict__ ctx) {
    int bh = blockIdx.x;
    int b = bh >> 3, hh = bh & 7;
    int tid = threadIdx.x;
    int role = tid >> 8;            // 0 = compute (waves 0-3), 1 = stage (4-7)
    int htid = tid & 255;
    int lane = htid & 63;
    int wv = htid >> 6;             // wave within role group
    int ri = wv * 8 + (lane >> 3);
    int c = lane & 7;
    bool cz = (c == 0);
    // double-buffered staging arrays (ks rows 64/65 = loadp pad)
    __shared__ __align__(16) float ks[2][66][36], qs[2][66][36], vs[2][66][36],
                                   bs[2][66][36], as_[2][66][36];
    __shared__ __align__(16) float cpair[2][33][4]; // [pair][c12,k1q1,k1q2,k2q2]
    __shared__ __align__(16) float cs[64][32];      // compute-only, single
    float4 S = *(const float4*)(S_in + ((size_t)bh * 32 + ri) * 32 + c * 4);

    int sc4 = htid & 7, sr0 = htid >> 3;   // staging map: token rows sr0, sr0+32
    float4 bB = *(const float4*)(bbias + hh * 32 + sc4 * 4);
    float4 bA = *(const float4*)(abias + hh * 32 + sc4 * 4);

    struct Pair {
        float4 k1, k2, q1, q2;
        float a1, a2, b1, b2, bv1, bv2;
        float c12, cq11, cq12, cq22;
    };

    auto dot4 = [](float4 s, float4 k) {
        return fmaf(s.w, k.w, fmaf(s.z, k.z, fmaf(s.y, k.y, s.x * k.x)));
    };

    // ---- stage one 64-token chunk into buffer `buf` (role-1 waves) ----
    auto stage_chunk = [&](int c0, int buf) {
        float (*ksH)[36] = ks[buf];
        float (*qsH)[36] = qs[buf];
        float (*vsH)[36] = vs[buf];
        float (*bsH)[36] = bs[buf];
        float (*asH)[36] = as_[buf];
        float (*cpH)[4]  = cpair[buf];
        const float* Pb = P + ((size_t)(b * 1024 + c0) * 1536) + hh * 32 + sc4 * 4;
#pragma unroll
        for (int it = 0; it < 2; ++it) {
            int tok = sr0 + it * 32;
            const float* pg = Pb + (size_t)tok * 1536;
            float4 kv = *(const float4*)(pg);
            float4 vv = *(const float4*)(pg + 256);
            float4 qv = *(const float4*)(pg + 512);
            float4 bv = *(const float4*)(pg + 768);
            float4 av = *(const float4*)(pg + 1024);
            float ss = kv.x * kv.x + kv.y * kv.y + kv.z * kv.z + kv.w * kv.w;
            ss = sum8(ss);
            float rn = 1.f / fmaxf(sqrtf(ss), 1e-12f);
            kv.x *= rn; kv.y *= rn; kv.z *= rn; kv.w *= rn;
            float4 bo, ao;
            bo.x = 1.f / (1.f + __expf(-(bv.x + bB.x)));
            bo.y = 1.f / (1.f + __expf(-(bv.y + bB.y)));
            bo.z = 1.f / (1.f + __expf(-(bv.z + bB.z)));
            bo.w = 1.f / (1.f + __expf(-(bv.w + bB.w)));
            ao.x = 1.f / (1.f + __expf(-(av.x + bA.x)));
            ao.y = 1.f / (1.f + __expf(-(av.y + bA.y)));
            ao.z = 1.f / (1.f + __expf(-(av.z + bA.z)));
            ao.w = 1.f / (1.f + __expf(-(av.w + bA.w)));
            float4 vo;
            vo.x = bo.x * vv.x; vo.y = bo.y * vv.y;
            vo.z = bo.z * vv.z; vo.w = bo.w * vv.w;
            // pair-shared dots: tokens 2j/2j+1 in adjacent 8-lane groups
            float kq = sum8(kv.x * qv.x + kv.y * qv.y + kv.z * qv.z + kv.w * qv.w);
            float4 ko, qo;
            ko.x = __shfl_xor(kv.x, 8); ko.y = __shfl_xor(kv.y, 8);
            ko.z = __shfl_xor(kv.z, 8); ko.w = __shfl_xor(kv.w, 8);
            qo.x = __shfl_xor(qv.x, 8); qo.y = __shfl_xor(qv.y, 8);
            qo.z = __shfl_xor(qv.z, 8); qo.w = __shfl_xor(qv.w, 8);
            float ckk = sum8(kv.x * ko.x + kv.y * ko.y + kv.z * ko.z + kv.w * ko.w);
            float ckq = sum8(kv.x * qo.x + kv.y * qo.y + kv.z * qo.z + kv.w * qo.w);
            *(float4*)&ksH[tok][sc4 * 4] = kv;
            *(float4*)&vsH[tok][sc4 * 4] = vo;
            *(float4*)&qsH[tok][sc4 * 4] = qv;
            *(float4*)&bsH[tok][sc4 * 4] = bo;
            *(float4*)&asH[tok][sc4 * 4] = ao;
            if ((htid & 7) == 0) {
                int pairi = tok >> 1;
                if (!(tok & 1)) {
                    cpH[pairi][0] = ckk;   // k1.k2
                    cpH[pairi][1] = kq;    // k1.q1
                    cpH[pairi][2] = ckq;   // k1.q2
                } else {
                    cpH[pairi][3] = kq;    // k2.q2
                }
            }
        }
    };

    // ---- scan one staged chunk from buffer `buf` (role-0 waves) ----
    auto scan_chunk = [&](int c0, int buf) {
        float (*ksH)[36] = ks[buf];
        float (*qsH)[36] = qs[buf];
        float (*vsH)[36] = vs[buf];
        float (*bsH)[36] = bs[buf];
        float (*asH)[36] = as_[buf];
        float (*cpH)[4]  = cpair[buf];
        auto loadp = [&](int t, Pair& Pr) {
            Pr.k1 = *(const float4*)&ksH[2 * t][c * 4];
            Pr.k2 = *(const float4*)&ksH[2 * t + 1][c * 4];
            Pr.q1 = *(const float4*)&qsH[2 * t][c * 4];
            Pr.q2 = *(const float4*)&qsH[2 * t + 1][c * 4];
            Pr.a1 = asH[2 * t][ri];  Pr.a2 = asH[2 * t + 1][ri];
            Pr.b1 = bsH[2 * t][ri];  Pr.b2 = bsH[2 * t + 1][ri];
            Pr.bv1 = vsH[2 * t][ri]; Pr.bv2 = vsH[2 * t + 1][ri];
            float4 cp = *(const float4*)&cpH[t][0];
            Pr.c12 = cp.x; Pr.cq11 = cp.y; Pr.cq12 = cp.z; Pr.cq22 = cp.w;
        };
        auto stepp = [&](const Pair& Pr, int t) {
            float d1  = sum8(dot4(S, Pr.k1));
            float d2  = sum8(dot4(S, Pr.k2));
            float dq1 = sum8(dot4(S, Pr.q1));
            float dq2 = sum8(dot4(S, Pr.q2));
            float u1 = fmaf(-(Pr.b1 * Pr.a1), d1, Pr.bv1);
            float au1 = Pr.a2 * u1;
            float A = Pr.a1 * Pr.a2;
            float pred2 = fmaf(au1, Pr.c12, A * d2);
            float u2 = fmaf(-Pr.b2, pred2, Pr.bv2);
            S.x = fmaf(u2, Pr.k2.x, fmaf(au1, Pr.k1.x, A * S.x));
            S.y = fmaf(u2, Pr.k2.y, fmaf(au1, Pr.k1.y, A * S.y));
            S.z = fmaf(u2, Pr.k2.z, fmaf(au1, Pr.k1.z, A * S.z));
            S.w = fmaf(u2, Pr.k2.w, fmaf(au1, Pr.k1.w, A * S.w));
            if (cz) {
                cs[2 * t][ri]     = fmaf(u1, Pr.cq11, Pr.a1 * dq1);
                cs[2 * t + 1][ri] = fmaf(u2, Pr.cq22, fmaf(au1, Pr.cq12, A * dq2));
            }
        };
        Pair PA, PB;
        loadp(0, PA);
        for (int t = 0; t < 32; t += 2) {
            loadp(t + 1, PB);
            stepp(PA, t);
            loadp(t + 2, PA);   // t==30 -> pair 32: pad rows 64/65, cpair[32]
            stepp(PB, t + 1);
        }
        // per-wave-own-rows ctx store: wave wv wrote cs[t][8wv..8wv+7]
        int gbase = b * 1024 + c0;
#pragma unroll
        for (int it = 0; it < 2; ++it) {
            int e = lane + it * 64;
            int t = e >> 1, j4 = wv * 2 + (e & 1);
            float4 val = *(const float4*)&cs[t][j4 * 4];
            *(float4*)(ctx + (size_t)(gbase + t) * 256 + hh * 32 + j4 * 4) = val;
        }
    };

    // ---- producer/consumer chunk pipeline ----
    if (role == 1) stage_chunk(0, 0);
    __syncthreads();
    for (int ch = 0; ch < 16; ++ch) {
        if (role == 1) {
            if (ch + 1 < 16) stage_chunk((ch + 1) * 64, (ch + 1) & 1);
        } else {
            scan_chunk(ch * 64, ch & 1);
        }
        __syncthreads();
    }
    if (role == 0)
        *(float4*)(S_out + ((size_t)bh * 32 + ri) * 32 + c * 4) = S;
}

// ------------- ctxbf = bf16(rmsnorm(ctx,nw)*silu(gate)), gate in P@1280 ----
__global__ void ctx_post(const float* __restrict__ ctx, const float* __restrict__ P,
                         const float* __restrict__ nw, bf16* __restrict__ out) {
    int row = blockIdx.x, t = threadIdx.x;  // 64 threads
    float4 x = ((const float4*)(ctx + (size_t)row * SDIMM))[t];
    float s = x.x * x.x + x.y * x.y + x.z * x.z + x.w * x.w;
    for (int m = 1; m < 64; m <<= 1) s += __shfl_xor(s, m);
    float r = rsqrtf(s * (1.f / 256.f) + 1e-6f);
    float4 n = ((const float4*)nw)[t];
    float4 g = ((const float4*)(P + (size_t)row * 1536 + 1280))[t];
    BF4 u;
    u.h[0] = (bf16)(x.x * r * n.x * (g.x / (1.f + __expf(-g.x))));
    u.h[1] = (bf16)(x.y * r * n.y * (g.y / (1.f + __expf(-g.y))));
    u.h[2] = (bf16)(x.z * r * n.z * (g.z / (1.f + __expf(-g.z))));
    u.h[3] = (bf16)(x.w * r * n.w * (g.w / (1.f + __expf(-g.w))));
    ((short4*)(out + (size_t)row * SDIMM))[t] = u.p;
}

// ---------------------------------------------------------------------------
extern "C" void kernel_launch(void* const* d_in, const int* in_sizes, int n_in,
                              void* d_out, int out_size, void* d_ws, size_t ws_size,
                              hipStream_t stream) {
    (void)in_sizes; (void)n_in; (void)out_size; (void)ws_size;
    const int* ids = (const int*)d_in[0];
    const float* state = (const float*)d_in[1];
    const float* embedw = (const float*)d_in[2];
    auto F = [&](int i) { return (const float*)d_in[i]; };

    char* wsb = (char*)d_ws;
    const size_t MB = 1048576;
    float* H    = (float*)(wsb);                 // 0-8 MB
    bf16*  XNbf = (bf16*)(wsb + 8 * MB);         // 8-12 (alias ctxf in delta)
    float* ctxf = (float*)(wsb + 8 * MB);
    bf16*  Hbf  = (bf16*)(wsb + 12 * MB);        // 12-16 (alias ctxb)
    bf16*  ctxb = (bf16*)(wsb + 12 * MB);
    float* P    = (float*)(wsb + 16 * MB);       // 16-40 (delta proj f32)
    bf16*  Obf  = (bf16*)(wsb + 40 * MB);        // 40-44 attn out
    bf16*  Qbuf = (bf16*)(wsb + 44 * MB);        // 44-48
    bf16*  Kbuf = (bf16*)(wsb + 48 * MB);        // 48-52
    bf16*  Vtb  = (bf16*)(wsb + 52 * MB);        // 52-56
    bf16*  A1b  = (bf16*)(wsb + 44 * MB);        // alias Q/K/Vt (dead after attn)
    float* cosT = (float*)(wsb + 58 * MB);
    float* sinT = cosT + 32768;
    float* Sbuf = sinT + 32768;
    char*  wbase = wsb + 59 * MB;
    bf16* wqkv  = (bf16*)(wbase);                        // 6x1536x512
    bf16* wob   = (bf16*)(wbase + 9437184);              // 6x512x512
    bf16* wgu   = (bf16*)(wbase + 12582912);             // 6x3072x512 interleaved
    bf16* wdnb  = (bf16*)(wbase + 31457280);             // 6x512x1536
    bf16* wdR   = (bf16*)(wbase + 40894464);             // 1536x512
    bf16* woutR = (bf16*)(wbase + 42467328);             // 512x256
    bf16* wdW   = (bf16*)(wbase + 42729472);             // 1536x512
    bf16* woutW = (bf16*)(wbase + 44302336);             // 512x256
    bf16* embp  = (bf16*)(wbase + 44564480);             // 128x512 padded

    float* out = (float*)d_out;
    float* logits = out;
    float* Sout = out + 4096 * VOCN;

    // 128x128-tile launches
    auto G0 = [&](const bf16* A, const bf16* B, float* C, int M, int N, int K, int Nreal) {
        gemm_bf16<0><<<dim3(N / 128, M / 128), 256, 0, stream>>>(
            A, B, C, nullptr, nullptr, nullptr, nullptr, nullptr, nullptr, M, N, K, Nreal);
    };
    auto G4 = [&](const bf16* A, const bf16* B, bf16* Cb, int M, int N, int K, int Nreal) {
        gemm_bf16<4><<<dim3(N / 128, M / 128), 256, 0, stream>>>(
            A, B, nullptr, Cb, nullptr, nullptr, nullptr, nullptr, nullptr, M, N, K, Nreal);
    };
    auto G5 = [&](const bf16* A, const bf16* B, int M, int N, int K) {
        gemm_bf16<5><<<dim3(N / 128, M / 128), 256, 0, stream>>>(
            A, B, nullptr, nullptr, cosT, sinT, Qbuf, Kbuf, Vtb, M, N, K, N);
    };
    // 64x128-tile accumulate
    auto G1s = [&](const bf16* A, const bf16* B, float* C, int M, int N, int K) {
        gemm64_bf16<1><<<dim3(N / 128, M / 64), 256, 0, stream>>>(A, B, C, M, N, K, N);
    };
    auto G0s = [&](const bf16* A, const bf16* B, float* C, int M, int N, int K, int Nreal) {
        gemm64_bf16<0><<<dim3(N / 128, M / 64), 256, 0, stream>>>(A, B, C, M, N, K, Nreal);
    };
    auto CP = [&](const float* s, bf16* d, int n4) {
        cast_plain<<<(n4 + 255) / 256, 256, 0, stream>>>(s, d, n4);
    };

    // ---- weight casts ----
    cast_qkv<<<4608, 256, 0, stream>>>(F(24), F(25), F(26), wqkv);
    CP(F(27), wob, 393216);
    cast_gu<<<9216, 256, 0, stream>>>(F(29), F(30), wgu);
    CP(F(31), wdnb, 1179648);
    cast6<<<768, 256, 0, stream>>>(F(3), F(4), F(5), F(6), F(8), F(12), wdR);
    CP(F(10), woutR, 32768);
    cast6<<<768, 256, 0, stream>>>(F(13), F(14), F(15), F(16), F(18), F(22), wdW);
    CP(F(20), woutW, 32768);
    cast_embed_pad<<<64, 256, 0, stream>>>(embedw, embp);

    rope_tables_k<<<128, 256, 0, stream>>>(cosT, sinT);
    embed_k<<<4096, 128, 0, stream>>>(ids, embedw, H);

    // ---- delta read ----
    CP(H, Hbf, 524288);
    G0(Hbf, wdR, P, 4096, 1536, 512, 1536);
    delta_scan<<<32, 512, 0, stream>>>(P, state, F(7), F(9), Sbuf, ctxf);
    ctx_post<<<4096, 64, 0, stream>>>(ctxf, P, F(11), ctxb);
    G1s(ctxb, woutR, H, 4096, 512, 256);

    for (int i = 0; i < 6; ++i) {
        rmsnorm512<<<4096, 128, 0, stream>>>(H, F(23) + (size_t)i * 512, XNbf);
        G5(XNbf, wqkv + (size_t)i * 1536 * 512, 4096, 1536, 512);
        attn_mfma<<<dim3(16, 8, 4), 256, 0, stream>>>(Qbuf, Kbuf, Vtb, Obf);
        G1s(Obf, wob + (size_t)i * 512 * 512, H, 4096, 512, 512);
        rmsnorm512<<<4096, 128, 0, stream>>>(H, F(28) + (size_t)i * 512, XNbf);
        G4(XNbf, wgu + (size_t)i * 3072 * 512, A1b, 4096, 3072, 512, 1536);
        G1s(A1b, wdnb + (size_t)i * 512 * 1536, H, 4096, 512, 1536);
    }

    // ---- delta write ----
    CP(H, Hbf, 524288);
    G0(Hbf, wdW, P, 4096, 1536, 512, 1536);
    delta_scan<<<32, 512, 0, stream>>>(P, Sbuf, F(17), F(19), Sout, ctxf);
    ctx_post<<<4096, 64, 0, stream>>>(ctxf, P, F(21), ctxb);
    G1s(ctxb, woutW, H, 4096, 512, 256);

    rmsnorm512<<<4096, 128, 0, stream>>>(H, F(32), XNbf);
    G0s(XNbf, embp, logits, 4096, 128, 512, VOCN);
}

// Round 13
// 1120.600 us; speedup vs baseline: 1.1138x; 1.0602x over previous
//
#include <hip/hip_runtime.h>
#include <hip/hip_bf16.h>
#include <math.h>

// ---------------------------------------------------------------------------
// BashTransformer forward on MI355X. Round 21 (= r20 + compile fix: the
// standalone cast_plain kernel is retained for the two RUNTIME H->Hbf casts;
// only the startup weight casts moved into cast_all).
// (1) cast_all mega-kernel: 11 startup launches -> 1 (bit-identical).
// (2) attn load-balance: qt -> 15-qt for b&2 so each CU pair gets 17 tiles.
// (3) T5 setprio around attn MFMA clusters.
// r19 GEMM/V-store, r17 T1 swizzle, r16 gemm64 dbuf, r13 delta_scan retained.
// ---------------------------------------------------------------------------

#define LSEQ 1024
#define BATCH 4
#define HIDDEN 512
#define NHEAD 8
#define HDIM 64
#define SHEAD 8
#define SDHD 32
#define SDIMM 256
#define FFND 1536
#define VOCN 63
#define ATTS 72   // attn LDS row stride (elems): 144B = 16B-aligned, 2-way banks

typedef __bf16 bf16;
typedef __attribute__((ext_vector_type(8))) __bf16 bf16x8;
typedef __attribute__((ext_vector_type(4))) float floatx4;

union BF4 { bf16 h[4]; short4 p; };

__device__ __forceinline__ void gload16(const void* g, const void* l) {
    __builtin_amdgcn_global_load_lds(
        (__attribute__((address_space(1))) unsigned int*)(uintptr_t)g,
        (__attribute__((address_space(3))) unsigned int*)(unsigned int)(uintptr_t)l,
        16, 0, 0);
}

// sum over aligned groups of 8 lanes, pure DPP (VALU pipe, no LDS counters)
__device__ __forceinline__ float sum8(float x) {
    x += __int_as_float(__builtin_amdgcn_mov_dpp(__float_as_int(x), 0xB1, 0xF, 0xF, true));
    x += __int_as_float(__builtin_amdgcn_mov_dpp(__float_as_int(x), 0x4E, 0xF, 0xF, true));
    x += __int_as_float(__builtin_amdgcn_mov_dpp(__float_as_int(x), 0x141, 0xF, 0xF, true));
    return x;
}

// T1: bijective XCD-aware remap (m204). Blocks with equal orig%8 (same XCD
// under round-robin dispatch) get a CONTIGUOUS range of logical ids, so
// x-major neighbors sharing operand panels stay on one XCD's L2.
__device__ __forceinline__ int xcd_swz(int lin, int nwg) {
    int q = nwg >> 3, r = nwg & 7;
    int xcd = lin & 7, sub = lin >> 3;
    return (xcd < r ? xcd * (q + 1) : r * (q + 1) + (xcd - r) * q) + sub;
}

// ------------------------------- casts -------------------------------------
// runtime H -> Hbf cast (dynamic data; cannot live in the startup mega-kernel)
__global__ void cast_plain(const float* __restrict__ s, bf16* __restrict__ d, int n4) {
    int i = blockIdx.x * 256 + threadIdx.x;
    if (i >= n4) return;
    float4 v = ((const float4*)s)[i];
    BF4 u;
    u.h[0] = (bf16)v.x; u.h[1] = (bf16)v.y; u.h[2] = (bf16)v.z; u.h[3] = (bf16)v.w;
    ((short4*)d)[i] = u.p;
}

// ------------------- fused casts + rope tables + embedding -----------------
// One launch, block-range dispatch (r15-verified). Region layout:
//   [    0, 4608) cast_qkv      [ 4608, 6144) wob      [ 6144,15360) cast_gu
//   [15360,19968) wdnb          [19968,20736) cast6 R  [20736,20864) woutR
//   [20864,21632) cast6 W       [21632,21760) woutW    [21760,21824) embp
//   [21824,21952) rope          [21952,24000) embed (2 tokens/block)
struct CastArgs {
    const float *wq, *wk, *wv, *wob, *wg, *wu, *wdn;
    const float *r0, *r1, *r2, *r3, *r4, *r5, *woutR;
    const float *w0, *w1, *w2, *w3, *w4, *w5, *woutW;
    const float *emb; const int *ids;
    bf16 *wqkvD, *wobD, *wguD, *wdnbD, *wdRD, *woutRD, *wdWD, *woutWD, *embpD;
    float *cosT, *sinT, *H;
};

__device__ __forceinline__ void cast4(const float* s, bf16* d, int i) {
    float4 v = ((const float4*)s)[i];
    BF4 u;
    u.h[0] = (bf16)v.x; u.h[1] = (bf16)v.y; u.h[2] = (bf16)v.z; u.h[3] = (bf16)v.w;
    ((short4*)d)[i] = u.p;
}

__global__ void cast_all(CastArgs a) {
    int bx = blockIdx.x, tid = threadIdx.x;
    if (bx < 4608) {                                   // qkv fuse
        int idx = bx * 256 + tid;
        int which = idx / 393216;
        int rem = idx - which * 393216;
        const float* s = which == 0 ? a.wq : which == 1 ? a.wk : a.wv;
        int layer = rem >> 16, rr = rem & 65535;
        int r = rr >> 7, c4 = rr & 127;
        float4 x = ((const float4*)s)[rem];
        BF4 u;
        u.h[0] = (bf16)x.x; u.h[1] = (bf16)x.y; u.h[2] = (bf16)x.z; u.h[3] = (bf16)x.w;
        ((short4*)a.wqkvD)[((size_t)layer * 1536 + which * 512 + r) * 128 + c4] = u.p;
    } else if (bx < 6144) {                            // wob plain
        cast4(a.wob, a.wobD, (bx - 4608) * 256 + tid);
    } else if (bx < 15360) {                           // gate/up interleave
        int idx = (bx - 6144) * 256 + tid;
        int which = idx / 1179648;
        int rem = idx - which * 1179648;
        const float* s = which == 0 ? a.wg : a.wu;
        int layer = rem / 196608, rr = rem - layer * 196608;
        int r = rr >> 7, c4 = rr & 127;
        float4 x = ((const float4*)s)[rem];
        BF4 u;
        u.h[0] = (bf16)x.x; u.h[1] = (bf16)x.y; u.h[2] = (bf16)x.z; u.h[3] = (bf16)x.w;
        ((short4*)a.wguD)[((size_t)layer * 3072 + r * 2 + which) * 128 + c4] = u.p;
    } else if (bx < 19968) {                           // wdnb plain
        cast4(a.wdn, a.wdnbD, (bx - 15360) * 256 + tid);
    } else if (bx < 20736) {                           // cast6 read-set
        int i = (bx - 19968) * 256 + tid;
        int which = i >> 15, loc = i & 32767;
        const float* s = which == 0 ? a.r0 : which == 1 ? a.r1 : which == 2 ? a.r2
                        : which == 3 ? a.r3 : which == 4 ? a.r4 : a.r5;
        cast4(s, a.wdRD + (size_t)which * 131072, loc);
    } else if (bx < 20864) {                           // woutR
        cast4(a.woutR, a.woutRD, (bx - 20736) * 256 + tid);
    } else if (bx < 21632) {                           // cast6 write-set
        int i = (bx - 20864) * 256 + tid;
        int which = i >> 15, loc = i & 32767;
        const float* s = which == 0 ? a.w0 : which == 1 ? a.w1 : which == 2 ? a.w2
                        : which == 3 ? a.w3 : which == 4 ? a.w4 : a.w5;
        cast4(s, a.wdWD + (size_t)which * 131072, loc);
    } else if (bx < 21760) {                           // woutW
        cast4(a.woutW, a.woutWD, (bx - 21632) * 256 + tid);
    } else if (bx < 21824) {                           // embed pad
        int i = (bx - 21760) * 256 + tid;
        int row = i >> 7, c4 = i & 127;
        BF4 u;
        if (row < VOCN) {
            float4 v = ((const float4*)a.emb)[row * 128 + c4];
            u.h[0] = (bf16)v.x; u.h[1] = (bf16)v.y; u.h[2] = (bf16)v.z; u.h[3] = (bf16)v.w;
        } else {
            u.h[0] = (bf16)0.f; u.h[1] = (bf16)0.f; u.h[2] = (bf16)0.f; u.h[3] = (bf16)0.f;
        }
        ((short4*)a.embpD)[i] = u.p;
    } else if (bx < 21952) {                           // rope tables
        int idx = (bx - 21824) * 256 + tid;
        int l = idx >> 5, d = idx & 31;
        double ang = (double)l * pow(500000.0, -(double)(2 * d) / 64.0);
        a.cosT[idx] = (float)cos(ang);
        a.sinT[idx] = (float)sin(ang);
    } else {                                           // embedding (2 tok/blk)
        int tok = (bx - 21952) * 2 + (tid >> 7);
        int id = a.ids[tok];
        ((float4*)(a.H + (size_t)tok * HIDDEN))[tid & 127] =
            ((const float4*)(a.emb + (size_t)id * HIDDEN))[tid & 127];
    }
}

// ------------------------------- rmsnorm -> bf16 ---------------------------
__global__ void rmsnorm512(const float* __restrict__ in, const float* __restrict__ w,
                           bf16* __restrict__ out) {
    int row = blockIdx.x, t = threadIdx.x;     // 128 threads
    float4 x = ((const float4*)(in + (size_t)row * 512))[t];
    float s = x.x * x.x + x.y * x.y + x.z * x.z + x.w * x.w;
    for (int m = 1; m < 64; m <<= 1) s += __shfl_xor(s, m);
    __shared__ float red[2];
    if ((t & 63) == 0) red[t >> 6] = s;
    __syncthreads();
    float tot = red[0] + red[1];
    float r = rsqrtf(tot * (1.f / 512.f) + 1e-6f);
    float4 wv = ((const float4*)w)[t];
    BF4 u;
    u.h[0] = (bf16)(x.x * r * wv.x); u.h[1] = (bf16)(x.y * r * wv.y);
    u.h[2] = (bf16)(x.z * r * wv.z); u.h[3] = (bf16)(x.w * r * wv.w);
    ((short4*)(out + (size_t)row * 512))[t] = u.p;
}

// ------------------------------- bf16 MFMA GEMM (128x128) ------------------
// C = A(bf16, MxK rm) @ B(bf16, NxK rm)^T. 128x128 tile, BK=64, 4 waves.
// LDS layout XOR-swizzled by 16B unit (pre-swizzled global source; r14).
// T1 XCD-aware block swizzle (r17). Single-buffered.
// MODE 0: C(f32)=v
// MODE 4: gate/up interleaved cols; Cb[row*Nreal+col/2]=bf16(silu(g)*u)
// MODE 5: fused QKV epilogue: RoPE(q,k)->Qb/Kb bf16 [bh][l][64]; V via
//         per-wave LDS transpose (r19) -> coalesced 16B Vtb stores.
template <int MODE>
__global__ __launch_bounds__(256) void gemm_bf16(const bf16* __restrict__ A,
                                                 const bf16* __restrict__ B,
                                                 float* __restrict__ C,
                                                 bf16* __restrict__ Cb,
                                                 const float* __restrict__ cosT,
                                                 const float* __restrict__ sinT,
                                                 bf16* __restrict__ Qb,
                                                 bf16* __restrict__ Kb,
                                                 bf16* __restrict__ Vtb,
                                                 int M, int N, int K, int Nreal) {
    __shared__ bf16 As[128 * 64];
    __shared__ bf16 Bs[128 * 64];
    const int tid = threadIdx.x;
    const int wave = tid >> 6, lane = tid & 63;
    const int nx = gridDim.x;
    const int wg = xcd_swz(blockIdx.y * nx + blockIdx.x, nx * gridDim.y);
    const int row0 = (wg / nx) * 128, col0 = (wg % nx) * 128;
    floatx4 acc[4][4];
#pragma unroll
    for (int i = 0; i < 4; ++i)
#pragma unroll
        for (int j = 0; j < 4; ++j) acc[i][j] = (floatx4){0.f, 0.f, 0.f, 0.f};
    const int m0 = (wave & 1) * 64, n0 = (wave >> 1) * 64;
    const int sr = tid >> 3;                       // 32 rows per staging call
    const int ske = ((tid & 7) ^ (sr & 7)) * 8;    // pre-swizzled k offset (elems)
    char* AsB = (char*)As;
    char* BsB = (char*)Bs;
    const int ldst = wave * 1024;
    const int ua0 = (((lane >> 4) + 0) ^ (lane & 7)) * 16;   // kk=0 unit byte
    const int ua1 = (((lane >> 4) + 4) ^ (lane & 7)) * 16;   // kk=1 unit byte

    for (int k0 = 0; k0 < K; k0 += 64) {
#pragma unroll
        for (int j = 0; j < 4; ++j) {
            gload16(A + (size_t)(row0 + j * 32 + sr) * K + ske + k0,
                    AsB + j * 4096 + ldst);
            gload16(B + (size_t)(col0 + j * 32 + sr) * K + ske + k0,
                    BsB + j * 4096 + ldst);
        }
        __syncthreads();
#pragma unroll
        for (int kk = 0; kk < 2; ++kk) {
            const int uu = kk ? ua1 : ua0;
            bf16x8 af[4], bfr[4];
#pragma unroll
            for (int mi = 0; mi < 4; ++mi)
                af[mi] = *(const bf16x8*)(AsB + (m0 + mi * 16 + (lane & 15)) * 128 + uu);
#pragma unroll
            for (int ni = 0; ni < 4; ++ni)
                bfr[ni] = *(const bf16x8*)(BsB + (n0 + ni * 16 + (lane & 15)) * 128 + uu);
#pragma unroll
            for (int mi = 0; mi < 4; ++mi)
#pragma unroll
                for (int ni = 0; ni < 4; ++ni)
                    acc[mi][ni] = __builtin_amdgcn_mfma_f32_16x16x32_bf16(af[mi], bfr[ni], acc[mi][ni], 0, 0, 0);
        }
        __syncthreads();
    }
    const int cr = (lane >> 4) * 4;
    const int cc = lane & 15;
    if (MODE == 5) {
        // wave-uniform 64-col span: segment + head fixed per wave
        int segbase = col0 + n0;
        int seg = segbase >> 9;           // 0=q 1=k 2=v
        int head = (segbase >> 6) & 7;
        if (seg < 2) {
#pragma unroll
            for (int mi = 0; mi < 4; ++mi) {
#pragma unroll
                for (int r = 0; r < 4; ++r) {
                    int row = row0 + m0 + mi * 16 + cr + r;
                    int b = row >> 10, l = row & 1023;
                    size_t bh = (size_t)(b * 8 + head);
                    float x0 = acc[mi][0][r], x1 = acc[mi][1][r];
                    float x2 = acc[mi][2][r], x3 = acc[mi][3][r];
                    float c0 = cosT[l * 32 + cc], c1 = cosT[l * 32 + 16 + cc];
                    float s0 = sinT[l * 32 + cc], s1 = sinT[l * 32 + 16 + cc];
                    bf16* dst = (seg == 0 ? Qb : Kb) + bh * 65536 + l * 64;
                    dst[cc]      = (bf16)(x0 * c0 - x2 * s0);
                    dst[16 + cc] = (bf16)(x1 * c1 - x3 * s1);
                    dst[32 + cc] = (bf16)(x2 * c0 + x0 * s0);
                    dst[48 + cc] = (bf16)(x3 * c1 + x1 * s1);
                }
            }
        } else {
            // r19: per-wave LDS transpose tile (8KB, As/Bs dead after K-loop).
            char* T = (wave < 2) ? ((char*)As + wave * 8192)
                                 : ((char*)Bs + (wave - 2) * 8192);
            int lb = row0 + m0;            // wave's token base (global row)
            int b = lb >> 10, l0 = lb & 1023;
            size_t bh = (size_t)(b * 8 + head);
            const int quad = lane >> 4;
            const int u = (quad >> 1);      // + mi*2 below
            const int h = (quad & 1) * 8;   // byte offset within unit
#pragma unroll
            for (int mi = 0; mi < 4; ++mi) {
#pragma unroll
                for (int ni = 0; ni < 4; ++ni) {
                    int d = ni * 16 + cc;
                    BF4 pk;
                    pk.h[0] = (bf16)acc[mi][ni][0];
                    pk.h[1] = (bf16)acc[mi][ni][1];
                    pk.h[2] = (bf16)acc[mi][ni][2];
                    pk.h[3] = (bf16)acc[mi][ni][3];
                    *(short4*)(T + d * 128 + ((mi * 2 + u) ^ (d & 7)) * 16 + h) = pk.p;
                }
            }
            int dl = lane >> 3, j = lane & 7;
#pragma unroll
            for (int i = 0; i < 8; ++i) {
                int d = i * 8 + dl;
                bf16x8 v = *(const bf16x8*)(T + d * 128 + ((j ^ dl) * 16));
                *(bf16x8*)(Vtb + bh * 65536 + (size_t)d * 1024 + l0 + j * 8) = v;
            }
        }
        return;
    }
#pragma unroll
    for (int mi = 0; mi < 4; ++mi) {
#pragma unroll
        for (int ni = 0; ni < 4; ++ni) {
#pragma unroll
            for (int r = 0; r < 4; ++r) {
                int row = row0 + m0 + mi * 16 + cr + r;
                int col = col0 + n0 + ni * 16 + cc;
                float v = acc[mi][ni][r];
                if (MODE == 4) {
                    float o = __shfl_xor(v, 1);
                    if (!(lane & 1)) {
                        float sg = v / (1.f + __expf(-v));
                        Cb[(size_t)row * Nreal + (col >> 1)] = (bf16)(sg * o);
                    }
                } else if (col < Nreal) {
                    size_t off = (size_t)row * Nreal + col;
                    if (MODE == 0) C[off] = v;
                }
            }
        }
    }
}

// ---------------------- 64x128-tile GEMM (accumulate) ----------------------
// Tile M=64, N=128, 4 waves each 32x64, BK=64, swizzled LDS (round 14).
// Round 16: LDS double-buffered (1 block/CU grids -> drains were exposed).
// Round 17: T1 XCD-aware block swizzle.
// MODE 0: C=v  MODE 1: C+=v
template <int MODE>
__global__ __launch_bounds__(256) void gemm64_bf16(const bf16* __restrict__ A,
                                                   const bf16* __restrict__ B,
                                                   float* __restrict__ C,
                                                   int M, int N, int K, int Nreal) {
    __shared__ bf16 As[2][64 * 64];
    __shared__ bf16 Bs[2][128 * 64];
    const int tid = threadIdx.x;
    const int wave = tid >> 6, lane = tid & 63;
    const int nx = gridDim.x;
    const int wg = xcd_swz(blockIdx.y * nx + blockIdx.x, nx * gridDim.y);
    const int row0 = (wg / nx) * 64, col0 = (wg % nx) * 128;
    floatx4 acc[2][4];
#pragma unroll
    for (int i = 0; i < 2; ++i)
#pragma unroll
        for (int j = 0; j < 4; ++j) acc[i][j] = (floatx4){0.f, 0.f, 0.f, 0.f};
    const int m0 = (wave & 1) * 32, n0 = (wave >> 1) * 64;
    const int sr = tid >> 3;
    const int ske = ((tid & 7) ^ (sr & 7)) * 8;
    const int ldst = wave * 1024;
    const int ua0 = (((lane >> 4) + 0) ^ (lane & 7)) * 16;
    const int ua1 = (((lane >> 4) + 4) ^ (lane & 7)) * 16;

    auto stage = [&](int k0, int buf) {
        char* AsB = (char*)As[buf];
        char* BsB = (char*)Bs[buf];
#pragma unroll
        for (int j = 0; j < 2; ++j)
            gload16(A + (size_t)(row0 + j * 32 + sr) * K + ske + k0,
                    AsB + j * 4096 + ldst);
#pragma unroll
        for (int j = 0; j < 4; ++j)
            gload16(B + (size_t)(col0 + j * 32 + sr) * K + ske + k0,
                    BsB + j * 4096 + ldst);
    };

    const int nk = K >> 6;
    stage(0, 0);
    __syncthreads();
    int cur = 0;
    for (int t = 0; t < nk; ++t, cur ^= 1) {
        if (t + 1 < nk) stage((t + 1) * 64, cur ^ 1);
        const char* AsB = (const char*)As[cur];
        const char* BsB = (const char*)Bs[cur];
#pragma unroll
        for (int kk = 0; kk < 2; ++kk) {
            const int uu = kk ? ua1 : ua0;
            bf16x8 af[2], bfr[4];
#pragma unroll
            for (int mi = 0; mi < 2; ++mi)
                af[mi] = *(const bf16x8*)(AsB + (m0 + mi * 16 + (lane & 15)) * 128 + uu);
#pragma unroll
            for (int ni = 0; ni < 4; ++ni)
                bfr[ni] = *(const bf16x8*)(BsB + (n0 + ni * 16 + (lane & 15)) * 128 + uu);
#pragma unroll
            for (int mi = 0; mi < 2; ++mi)
#pragma unroll
                for (int ni = 0; ni < 4; ++ni)
                    acc[mi][ni] = __builtin_amdgcn_mfma_f32_16x16x32_bf16(af[mi], bfr[ni], acc[mi][ni], 0, 0, 0);
        }
        __syncthreads();
    }
    const int cr = (lane >> 4) * 4;
    const int cc = lane & 15;
#pragma unroll
    for (int mi = 0; mi < 2; ++mi) {
#pragma unroll
        for (int ni = 0; ni < 4; ++ni) {
#pragma unroll
            for (int r = 0; r < 4; ++r) {
                int row = row0 + m0 + mi * 16 + cr + r;
                int col = col0 + n0 + ni * 16 + cc;
                if (col < Nreal) {
                    size_t off = (size_t)row * Nreal + col;
                    float v = acc[mi][ni][r];
                    if (MODE == 0) C[off] = v;
                    else C[off] += v;
                }
            }
        }
    }
}

// ------------------------- MFMA flash attention ----------------------------
// r20: causal load-balance — blocks with b&2 take qt' = 15-qt so each CU
// pair (same x,y; z differing by 2 = +256 block ids) processes qt + (15-qt)
// = 17 tiles instead of 2x the same qt (wall was 2x16). Bijective per-b.
// T5 setprio around MFMA clusters (2 blocks/CU -> waves at distinct phases).
__global__ __launch_bounds__(256) void attn_mfma(const bf16* __restrict__ Qb,
                                                 const bf16* __restrict__ Kb,
                                                 const bf16* __restrict__ Vtb,
                                                 bf16* __restrict__ O) {
    int qt = blockIdx.x, hh = blockIdx.y, b = blockIdx.z;
    if (b & 2) qt = gridDim.x - 1 - qt;    // complementary pairing
    int bh = b * 8 + hh;
    int q0 = qt * 64;
    const bf16* Qg = Qb + ((size_t)bh * 1024 + q0) * 64;
    const bf16* Kg = Kb + (size_t)bh * 1024 * 64;
    const bf16* Vg = Vtb + (size_t)bh * 64 * 1024;   // [64 d][1024 l]
    __shared__ bf16 Qs[64 * ATTS];
    __shared__ bf16 Ks[64 * ATTS];
    __shared__ bf16 Vs[64 * ATTS];
    __shared__ bf16 Ps[64 * ATTS];
    int tid = threadIdx.x, wave = tid >> 6, lane = tid & 63;
    int lr = lane & 15, quad = lane >> 4;

#pragma unroll
    for (int it = 0; it < 2; ++it) {
        int cidx = tid + it * 256;
        int row = cidx >> 3, ch = cidx & 7;
        *(bf16x8*)(Qs + row * ATTS + ch * 8) = *(const bf16x8*)(Qg + row * 64 + ch * 8);
    }
    float mrow[4], lrow[4];
    floatx4 Oacc[4];
#pragma unroll
    for (int r = 0; r < 4; ++r) { mrow[r] = -1e30f; lrow[r] = 0.f; }
#pragma unroll
    for (int d0 = 0; d0 < 4; ++d0) Oacc[d0] = (floatx4){0.f, 0.f, 0.f, 0.f};

    int ntiles = qt + 1;
    for (int t = 0; t < ntiles; ++t) {
        int kv0 = t * 64;
        __syncthreads();
#pragma unroll
        for (int it = 0; it < 2; ++it) {
            int cidx = tid + it * 256;
            int row = cidx >> 3, ch = cidx & 7;
            *(bf16x8*)(Ks + row * ATTS + ch * 8) =
                *(const bf16x8*)(Kg + (size_t)(kv0 + row) * 64 + ch * 8);
            *(bf16x8*)(Vs + row * ATTS + ch * 8) =
                *(const bf16x8*)(Vg + (size_t)row * 1024 + kv0 + ch * 8);
        }
        __syncthreads();
        bf16x8 aq[2];
#pragma unroll
        for (int kc = 0; kc < 2; ++kc)
            aq[kc] = *(const bf16x8*)(Qs + (wave * 16 + lr) * ATTS + kc * 32 + quad * 8);
        floatx4 sacc[4];
        __builtin_amdgcn_s_setprio(1);
#pragma unroll
        for (int n0 = 0; n0 < 4; ++n0) {
            bf16x8 bk0 = *(const bf16x8*)(Ks + (n0 * 16 + lr) * ATTS + quad * 8);
            bf16x8 bk1 = *(const bf16x8*)(Ks + (n0 * 16 + lr) * ATTS + 32 + quad * 8);
            floatx4 z = (floatx4){0.f, 0.f, 0.f, 0.f};
            z = __builtin_amdgcn_mfma_f32_16x16x32_bf16(aq[0], bk0, z, 0, 0, 0);
            sacc[n0] = __builtin_amdgcn_mfma_f32_16x16x32_bf16(aq[1], bk1, z, 0, 0, 0);
        }
        __builtin_amdgcn_s_setprio(0);
        float sv[4][4];
#pragma unroll
        for (int n0 = 0; n0 < 4; ++n0)
#pragma unroll
            for (int r = 0; r < 4; ++r) sv[n0][r] = sacc[n0][r] * 0.125f;
        if (t == ntiles - 1) {
#pragma unroll
            for (int n0 = 0; n0 < 4; ++n0)
#pragma unroll
                for (int r = 0; r < 4; ++r)
                    if (n0 * 16 + lr > wave * 16 + quad * 4 + r) sv[n0][r] = -1e30f;
        }
        float al[4];
#pragma unroll
        for (int r = 0; r < 4; ++r) {
            float tm = fmaxf(fmaxf(sv[0][r], sv[1][r]), fmaxf(sv[2][r], sv[3][r]));
            tm = fmaxf(tm, __shfl_xor(tm, 1));
            tm = fmaxf(tm, __shfl_xor(tm, 2));
            tm = fmaxf(tm, __shfl_xor(tm, 4));
            tm = fmaxf(tm, __shfl_xor(tm, 8));
            float mn = fmaxf(mrow[r], tm);
            al[r] = __expf(mrow[r] - mn);
            mrow[r] = mn;
        }
        float rs[4];
#pragma unroll
        for (int r = 0; r < 4; ++r) rs[r] = 0.f;
#pragma unroll
        for (int n0 = 0; n0 < 4; ++n0)
#pragma unroll
            for (int r = 0; r < 4; ++r) {
                float p = __expf(sv[n0][r] - mrow[r]);
                sv[n0][r] = p;
                rs[r] += p;
            }
#pragma unroll
        for (int r = 0; r < 4; ++r) {
            float t2 = rs[r];
            t2 += __shfl_xor(t2, 1);
            t2 += __shfl_xor(t2, 2);
            t2 += __shfl_xor(t2, 4);
            t2 += __shfl_xor(t2, 8);
            lrow[r] = lrow[r] * al[r] + t2;
        }
#pragma unroll
        for (int d0 = 0; d0 < 4; ++d0)
#pragma unroll
            for (int r = 0; r < 4; ++r) Oacc[d0][r] *= al[r];
#pragma unroll
        for (int n0 = 0; n0 < 4; ++n0)
#pragma unroll
            for (int r = 0; r < 4; ++r)
                Ps[(wave * 16 + quad * 4 + r) * ATTS + n0 * 16 + lr] = (bf16)sv[n0][r];
        bf16x8 ap[2];
#pragma unroll
        for (int kc = 0; kc < 2; ++kc)
            ap[kc] = *(const bf16x8*)(Ps + (wave * 16 + lr) * ATTS + kc * 32 + quad * 8);
        __builtin_amdgcn_s_setprio(1);
#pragma unroll
        for (int d0 = 0; d0 < 4; ++d0) {
            bf16x8 bv0 = *(const bf16x8*)(Vs + (d0 * 16 + lr) * ATTS + quad * 8);
            bf16x8 bv1 = *(const bf16x8*)(Vs + (d0 * 16 + lr) * ATTS + 32 + quad * 8);
            Oacc[d0] = __builtin_amdgcn_mfma_f32_16x16x32_bf16(ap[0], bv0, Oacc[d0], 0, 0, 0);
            Oacc[d0] = __builtin_amdgcn_mfma_f32_16x16x32_bf16(ap[1], bv1, Oacc[d0], 0, 0, 0);
        }
        __builtin_amdgcn_s_setprio(0);
    }
    float inv[4];
#pragma unroll
    for (int r = 0; r < 4; ++r) inv[r] = 1.f / lrow[r];
#pragma unroll
    for (int d0 = 0; d0 < 4; ++d0)
#pragma unroll
        for (int r = 0; r < 4; ++r) {
            int row = b * 1024 + q0 + wave * 16 + quad * 4 + r;
            int col = hh * 64 + d0 * 16 + lr;
            O[(size_t)row * 512 + col] = (bf16)(Oacc[d0][r] * inv[r]);
        }
}

// ------------------------------- delta scan --------------------------------
// Round 13 structure (verified, 95 us): 32 blocks x 512 threads. Waves 0-3
// (role 0) run the round-9 verified 2-token pair scan on chunk c; waves 4-7
// (role 1) stage chunk c+1 into the other LDS buffer. One barrier per chunk.
__global__ __launch_bounds__(512, 2) void delta_scan(
    const float* __restrict__ P, const float* __restrict__ S_in,
    const float* __restrict__ bbias, const float* __restrict__ abias,
    float* __restrict__ S_out, float* __restrict__ ctx) {
    int bh = blockIdx.x;
    int b = bh >> 3, hh = bh & 7;
    int tid = threadIdx.x;
    int role = tid >> 8;            // 0 = compute (waves 0-3), 1 = stage (4-7)
    int htid = tid & 255;
    int lane = htid & 63;
    int wv = htid >> 6;             // wave within role group
    int ri = wv * 8 + (lane >> 3);
    int c = lane & 7;
    bool cz = (c == 0);
    // double-buffered staging arrays (ks rows 64/65 = loadp pad)
    __shared__ __align__(16) float ks[2][66][36], qs[2][66][36], vs[2][66][36],
                                   bs[2][66][36], as_[2][66][36];
    __shared__ __align__(16) float cpair[2][33][4]; // [pair][c12,k1q1,k1q2,k2q2]
    __shared__ __align__(16) float cs[64][32];      // compute-only, single
    float4 S = *(const float4*)(S_in + ((size_t)bh * 32 + ri) * 32 + c * 4);

    int sc4 = htid & 7, sr0 = htid >> 3;   // staging map: token rows sr0, sr0+32
    float4 bB = *(const float4*)(bbias + hh * 32 + sc4 * 4);
    float4 bA = *(const float4*)(abias + hh * 32 + sc4 * 4);

    struct Pair {
        float4 k1, k2, q1, q2;
        float a1, a2, b1, b2, bv1, bv2;
        float c12, cq11, cq12, cq22;
    };

    auto dot4 = [](float4 s, float4 k) {
        return fmaf(s.w, k.w, fmaf(s.z, k.z, fmaf(s.y, k.y, s.x * k.x)));
    };

    // ---- stage one 64-token chunk into buffer `buf` (role-1 waves) ----
    auto stage_chunk = [&](int c0, int buf) {
        float (*ksH)[36] = ks[buf];
        float (*qsH)[36] = qs[buf];
        float (*vsH)[36] = vs[buf];
        float (*bsH)[36] = bs[buf];
        float (*asH)[36] = as_[buf];
        float (*cpH)[4]  = cpair[buf];
        const float* Pb = P + ((size_t)(b * 1024 + c0) * 1536) + hh * 32 + sc4 * 4;
#pragma unroll
        for (int it = 0; it < 2; ++it) {
            int tok = sr0 + it * 32;
            const float* pg = Pb + (size_t)tok * 1536;
            float4 kv = *(const float4*)(pg);
            float4 vv = *(const float4*)(pg + 256);
            float4 qv = *(const float4*)(pg + 512);
            float4 bv = *(const float4*)(pg + 768);
            float4 av = *(const float4*)(pg + 1024);
            float ss = kv.x * kv.x + kv.y * kv.y + kv.z * kv.z + kv.w * kv.w;
            ss = sum8(ss);
            float rn = 1.f / fmaxf(sqrtf(ss), 1e-12f);
            kv.x *= rn; kv.y *= rn; kv.z *= rn; kv.w *= rn;
            float4 bo, ao;
            bo.x = 1.f / (1.f + __expf(-(bv.x + bB.x)));
            bo.y = 1.f / (1.f + __expf(-(bv.y + bB.y)));
            bo.z = 1.f / (1.f + __expf(-(bv.z + bB.z)));
            bo.w = 1.f / (1.f + __expf(-(bv.w + bB.w)));
            ao.x = 1.f / (1.f + __expf(-(av.x + bA.x)));
            ao.y = 1.f / (1.f + __expf(-(av.y + bA.y)));
            ao.z = 1.f / (1.f + __expf(-(av.z + bA.z)));
            ao.w = 1.f / (1.f + __expf(-(av.w + bA.w)));
            float4 vo;
            vo.x = bo.x * vv.x; vo.y = bo.y * vv.y;
            vo.z = bo.z * vv.z; vo.w = bo.w * vv.w;
            // pair-shared dots: tokens 2j/2j+1 in adjacent 8-lane groups
            float kq = sum8(kv.x * qv.x + kv.y * qv.y + kv.z * qv.z + kv.w * qv.w);
            float4 ko, qo;
            ko.x = __shfl_xor(kv.x, 8); ko.y = __shfl_xor(kv.y, 8);
            ko.z = __shfl_xor(kv.z, 8); ko.w = __shfl_xor(kv.w, 8);
            qo.x = __shfl_xor(qv.x, 8); qo.y = __shfl_xor(qv.y, 8);
            qo.z = __shfl_xor(qv.z, 8); qo.w = __shfl_xor(qv.w, 8);
            float ckk = sum8(kv.x * ko.x + kv.y * ko.y + kv.z * ko.z + kv.w * ko.w);
            float ckq = sum8(kv.x * qo.x + kv.y * qo.y + kv.z * qo.z + kv.w * qo.w);
            *(float4*)&ksH[tok][sc4 * 4] = kv;
            *(float4*)&vsH[tok][sc4 * 4] = vo;
            *(float4*)&qsH[tok][sc4 * 4] = qv;
            *(float4*)&bsH[tok][sc4 * 4] = bo;
            *(float4*)&asH[tok][sc4 * 4] = ao;
            if ((htid & 7) == 0) {
                int pairi = tok >> 1;
                if (!(tok & 1)) {
                    cpH[pairi][0] = ckk;   // k1.k2
                    cpH[pairi][1] = kq;    // k1.q1
                    cpH[pairi][2] = ckq;   // k1.q2
                } else {
                    cpH[pairi][3] = kq;    // k2.q2
                }
            }
        }
    };

    // ---- scan one staged chunk from buffer `buf` (role-0 waves) ----
    auto scan_chunk = [&](int c0, int buf) {
        float (*ksH)[36] = ks[buf];
        float (*qsH)[36] = qs[buf];
        float (*vsH)[36] = vs[buf];
        float (*bsH)[36] = bs[buf];
        float (*asH)[36] = as_[buf];
        float (*cpH)[4]  = cpair[buf];
        auto loadp = [&](int t, Pair& Pr) {
            Pr.k1 = *(const float4*)&ksH[2 * t][c * 4];
            Pr.k2 = *(const float4*)&ksH[2 * t + 1][c * 4];
            Pr.q1 = *(const float4*)&qsH[2 * t][c * 4];
            Pr.q2 = *(const float4*)&qsH[2 * t + 1][c * 4];
            Pr.a1 = asH[2 * t][ri];  Pr.a2 = asH[2 * t + 1][ri];
            Pr.b1 = bsH[2 * t][ri];  Pr.b2 = bsH[2 * t + 1][ri];
            Pr.bv1 = vsH[2 * t][ri]; Pr.bv2 = vsH[2 * t + 1][ri];
            float4 cp = *(const float4*)&cpH[t][0];
            Pr.c12 = cp.x; Pr.cq11 = cp.y; Pr.cq12 = cp.z; Pr.cq22 = cp.w;
        };
        auto stepp = [&](const Pair& Pr, int t) {
            float d1  = sum8(dot4(S, Pr.k1));
            float d2  = sum8(dot4(S, Pr.k2));
            float dq1 = sum8(dot4(S, Pr.q1));
            float dq2 = sum8(dot4(S, Pr.q2));
            float u1 = fmaf(-(Pr.b1 * Pr.a1), d1, Pr.bv1);
            float au1 = Pr.a2 * u1;
            float A = Pr.a1 * Pr.a2;
            float pred2 = fmaf(au1, Pr.c12, A * d2);
            float u2 = fmaf(-Pr.b2, pred2, Pr.bv2);
            S.x = fmaf(u2, Pr.k2.x, fmaf(au1, Pr.k1.x, A * S.x));
            S.y = fmaf(u2, Pr.k2.y, fmaf(au1, Pr.k1.y, A * S.y));
            S.z = fmaf(u2, Pr.k2.z, fmaf(au1, Pr.k1.z, A * S.z));
            S.w = fmaf(u2, Pr.k2.w, fmaf(au1, Pr.k1.w, A * S.w));
            if (cz) {
                cs[2 * t][ri]     = fmaf(u1, Pr.cq11, Pr.a1 * dq1);
                cs[2 * t + 1][ri] = fmaf(u2, Pr.cq22, fmaf(au1, Pr.cq12, A * dq2));
            }
        };
        Pair PA, PB;
        loadp(0, PA);
        for (int t = 0; t < 32; t += 2) {
            loadp(t + 1, PB);
            stepp(PA, t);
            loadp(t + 2, PA);   // t==30 -> pair 32: pad rows 64/65, cpair[32]
            stepp(PB, t + 1);
        }
        // per-wave-own-rows ctx store: wave wv wrote cs[t][8wv..8wv+7]
        int gbase = b * 1024 + c0;
#pragma unroll
        for (int it = 0; it < 2; ++it) {
            int e = lane + it * 64;
            int t = e >> 1, j4 = wv * 2 + (e & 1);
            float4 val = *(const float4*)&cs[t][j4 * 4];
            *(float4*)(ctx + (size_t)(gbase + t) * 256 + hh * 32 + j4 * 4) = val;
        }
    };

    // ---- producer/consumer chunk pipeline ----
    if (role == 1) stage_chunk(0, 0);
    __syncthreads();
    for (int ch = 0; ch < 16; ++ch) {
        if (role == 1) {
            if (ch + 1 < 16) stage_chunk((ch + 1) * 64, (ch + 1) & 1);
        } else {
            scan_chunk(ch * 64, ch & 1);
        }
        __syncthreads();
    }
    if (role == 0)
        *(float4*)(S_out + ((size_t)bh * 32 + ri) * 32 + c * 4) = S;
}

// ------------- ctxbf = bf16(rmsnorm(ctx,nw)*silu(gate)), gate in P@1280 ----
__global__ void ctx_post(const float* __restrict__ ctx, const float* __restrict__ P,
                         const float* __restrict__ nw, bf16* __restrict__ out) {
    int row = blockIdx.x, t = threadIdx.x;  // 64 threads
    float4 x = ((const float4*)(ctx + (size_t)row * SDIMM))[t];
    float s = x.x * x.x + x.y * x.y + x.z * x.z + x.w * x.w;
    for (int m = 1; m < 64; m <<= 1) s += __shfl_xor(s, m);
    float r = rsqrtf(s * (1.f / 256.f) + 1e-6f);
    float4 n = ((const float4*)nw)[t];
    float4 g = ((const float4*)(P + (size_t)row * 1536 + 1280))[t];
    BF4 u;
    u.h[0] = (bf16)(x.x * r * n.x * (g.x / (1.f + __expf(-g.x))));
    u.h[1] = (bf16)(x.y * r * n.y * (g.y / (1.f + __expf(-g.y))));
    u.h[2] = (bf16)(x.z * r * n.z * (g.z / (1.f + __expf(-g.z))));
    u.h[3] = (bf16)(x.w * r * n.w * (g.w / (1.f + __expf(-g.w))));
    ((short4*)(out + (size_t)row * SDIMM))[t] = u.p;
}

// ---------------------------------------------------------------------------
extern "C" void kernel_launch(void* const* d_in, const int* in_sizes, int n_in,
                              void* d_out, int out_size, void* d_ws, size_t ws_size,
                              hipStream_t stream) {
    (void)in_sizes; (void)n_in; (void)out_size; (void)ws_size;
    const int* ids = (const int*)d_in[0];
    const float* state = (const float*)d_in[1];
    const float* embedw = (const float*)d_in[2];
    auto F = [&](int i) { return (const float*)d_in[i]; };

    char* wsb = (char*)d_ws;
    const size_t MB = 1048576;
    float* H    = (float*)(wsb);                 // 0-8 MB
    bf16*  XNbf = (bf16*)(wsb + 8 * MB);         // 8-12 (alias ctxf in delta)
    float* ctxf = (float*)(wsb + 8 * MB);
    bf16*  Hbf  = (bf16*)(wsb + 12 * MB);        // 12-16 (alias ctxb)
    bf16*  ctxb = (bf16*)(wsb + 12 * MB);
    float* P    = (float*)(wsb + 16 * MB);       // 16-40 (delta proj f32)
    bf16*  Obf  = (bf16*)(wsb + 40 * MB);        // 40-44 attn out
    bf16*  Qbuf = (bf16*)(wsb + 44 * MB);        // 44-48
    bf16*  Kbuf = (bf16*)(wsb + 48 * MB);        // 48-52
    bf16*  Vtb  = (bf16*)(wsb + 52 * MB);        // 52-56
    bf16*  A1b  = (bf16*)(wsb + 44 * MB);        // alias Q/K/Vt (dead after attn)
    float* cosT = (float*)(wsb + 58 * MB);
    float* sinT = cosT + 32768;
    float* Sbuf = sinT + 32768;
    char*  wbase = wsb + 59 * MB;
    bf16* wqkv  = (bf16*)(wbase);                        // 6x1536x512
    bf16* wob   = (bf16*)(wbase + 9437184);              // 6x512x512
    bf16* wgu   = (bf16*)(wbase + 12582912);             // 6x3072x512 interleaved
    bf16* wdnb  = (bf16*)(wbase + 31457280);             // 6x512x1536
    bf16* wdR   = (bf16*)(wbase + 40894464);             // 1536x512
    bf16* woutR = (bf16*)(wbase + 42467328);             // 512x256
    bf16* wdW   = (bf16*)(wbase + 42729472);             // 1536x512
    bf16* woutW = (bf16*)(wbase + 44302336);             // 512x256
    bf16* embp  = (bf16*)(wbase + 44564480);             // 128x512 padded

    float* out = (float*)d_out;
    float* logits = out;
    float* Sout = out + 4096 * VOCN;

    // 128x128-tile launches
    auto G0 = [&](const bf16* A, const bf16* B, float* C, int M, int N, int K, int Nreal) {
        gemm_bf16<0><<<dim3(N / 128, M / 128), 256, 0, stream>>>(
            A, B, C, nullptr, nullptr, nullptr, nullptr, nullptr, nullptr, M, N, K, Nreal);
    };
    auto G4 = [&](const bf16* A, const bf16* B, bf16* Cb, int M, int N, int K, int Nreal) {
        gemm_bf16<4><<<dim3(N / 128, M / 128), 256, 0, stream>>>(
            A, B, nullptr, Cb, nullptr, nullptr, nullptr, nullptr, nullptr, M, N, K, Nreal);
    };
    auto G5 = [&](const bf16* A, const bf16* B, int M, int N, int K) {
        gemm_bf16<5><<<dim3(N / 128, M / 128), 256, 0, stream>>>(
            A, B, nullptr, nullptr, cosT, sinT, Qbuf, Kbuf, Vtb, M, N, K, N);
    };
    // 64x128-tile accumulate
    auto G1s = [&](const bf16* A, const bf16* B, float* C, int M, int N, int K) {
        gemm64_bf16<1><<<dim3(N / 128, M / 64), 256, 0, stream>>>(A, B, C, M, N, K, N);
    };
    auto G0s = [&](const bf16* A, const bf16* B, float* C, int M, int N, int K, int Nreal) {
        gemm64_bf16<0><<<dim3(N / 128, M / 64), 256, 0, stream>>>(A, B, C, M, N, K, Nreal);
    };
    auto CP = [&](const float* s, bf16* d, int n4) {
        cast_plain<<<(n4 + 255) / 256, 256, 0, stream>>>(s, d, n4);
    };

    // ---- fused weight casts + rope + embedding (one launch, r15-verified) --
    CastArgs ca;
    ca.wq = F(24); ca.wk = F(25); ca.wv = F(26); ca.wob = F(27);
    ca.wg = F(29); ca.wu = F(30); ca.wdn = F(31);
    ca.r0 = F(3); ca.r1 = F(4); ca.r2 = F(5); ca.r3 = F(6); ca.r4 = F(8); ca.r5 = F(12);
    ca.woutR = F(10);
    ca.w0 = F(13); ca.w1 = F(14); ca.w2 = F(15); ca.w3 = F(16); ca.w4 = F(18); ca.w5 = F(22);
    ca.woutW = F(20);
    ca.emb = embedw; ca.ids = ids;
    ca.wqkvD = wqkv; ca.wobD = wob; ca.wguD = wgu; ca.wdnbD = wdnb;
    ca.wdRD = wdR; ca.woutRD = woutR; ca.wdWD = wdW; ca.woutWD = woutW;
    ca.embpD = embp; ca.cosT = cosT; ca.sinT = sinT; ca.H = H;
    cast_all<<<24000, 256, 0, stream>>>(ca);

    // ---- delta read ----
    CP(H, Hbf, 524288);
    G0(Hbf, wdR, P, 4096, 1536, 512, 1536);
    delta_scan<<<32, 512, 0, stream>>>(P, state, F(7), F(9), Sbuf, ctxf);
    ctx_post<<<4096, 64, 0, stream>>>(ctxf, P, F(11), ctxb);
    G1s(ctxb, woutR, H, 4096, 512, 256);

    for (int i = 0; i < 6; ++i) {
        rmsnorm512<<<4096, 128, 0, stream>>>(H, F(23) + (size_t)i * 512, XNbf);
        G5(XNbf, wqkv + (size_t)i * 1536 * 512, 4096, 1536, 512);
        attn_mfma<<<dim3(16, 8, 4), 256, 0, stream>>>(Qbuf, Kbuf, Vtb, Obf);
        G1s(Obf, wob + (size_t)i * 512 * 512, H, 4096, 512, 512);
        rmsnorm512<<<4096, 128, 0, stream>>>(H, F(28) + (size_t)i * 512, XNbf);
        G4(XNbf, wgu + (size_t)i * 3072 * 512, A1b, 4096, 3072, 512, 1536);
        G1s(A1b, wdnb + (size_t)i * 512 * 1536, H, 4096, 512, 1536);
    }

    // ---- delta write ----
    CP(H, Hbf, 524288);
    G0(Hbf, wdW, P, 4096, 1536, 512, 1536);
    delta_scan<<<32, 512, 0, stream>>>(P, Sbuf, F(17), F(19), Sout, ctxf);
    ctx_post<<<4096, 64, 0, stream>>>(ctxf, P, F(21), ctxb);
    G1s(ctxb, woutW, H, 4096, 512, 256);

    rmsnorm512<<<4096, 128, 0, stream>>>(H, F(32), XNbf);
    G0s(XNbf, embp, logits, 4096, 128, 512, VOCN);
}

// Round 15
// 1119.470 us; speedup vs baseline: 1.1149x; 1.0010x over previous
//
#include <hip/hip_runtime.h>
#include <hip/hip_bf16.h>
#include <math.h>

// ---------------------------------------------------------------------------
// BashTransformer forward on MI355X. Round 22 (resubmit; r23 was an infra
// failure): the two runtime H->Hbf casts fused into their producers
// (bit-exact): (a) cast_all's embed region now emits bf16 Hbf alongside
// f32 H; (b) gemm64 MODE 2 = accumulate + bf16 side-store of the final sum,
// used for the layer-5 down-proj (last H writer before delta-write).
// cast_plain removed. Everything else = r21 (cast_all, attn balance +
// setprio, r19 V-transpose, T1, gemm64 dbuf, r13 delta_scan).
// ---------------------------------------------------------------------------

#define LSEQ 1024
#define BATCH 4
#define HIDDEN 512
#define NHEAD 8
#define HDIM 64
#define SHEAD 8
#define SDHD 32
#define SDIMM 256
#define FFND 1536
#define VOCN 63
#define ATTS 72   // attn LDS row stride (elems): 144B = 16B-aligned, 2-way banks

typedef __bf16 bf16;
typedef __attribute__((ext_vector_type(8))) __bf16 bf16x8;
typedef __attribute__((ext_vector_type(4))) float floatx4;

union BF4 { bf16 h[4]; short4 p; };

__device__ __forceinline__ void gload16(const void* g, const void* l) {
    __builtin_amdgcn_global_load_lds(
        (__attribute__((address_space(1))) unsigned int*)(uintptr_t)g,
        (__attribute__((address_space(3))) unsigned int*)(unsigned int)(uintptr_t)l,
        16, 0, 0);
}

// sum over aligned groups of 8 lanes, pure DPP (VALU pipe, no LDS counters)
__device__ __forceinline__ float sum8(float x) {
    x += __int_as_float(__builtin_amdgcn_mov_dpp(__float_as_int(x), 0xB1, 0xF, 0xF, true));
    x += __int_as_float(__builtin_amdgcn_mov_dpp(__float_as_int(x), 0x4E, 0xF, 0xF, true));
    x += __int_as_float(__builtin_amdgcn_mov_dpp(__float_as_int(x), 0x141, 0xF, 0xF, true));
    return x;
}

// T1: bijective XCD-aware remap (m204). Blocks with equal orig%8 (same XCD
// under round-robin dispatch) get a CONTIGUOUS range of logical ids, so
// x-major neighbors sharing operand panels stay on one XCD's L2.
__device__ __forceinline__ int xcd_swz(int lin, int nwg) {
    int q = nwg >> 3, r = nwg & 7;
    int xcd = lin & 7, sub = lin >> 3;
    return (xcd < r ? xcd * (q + 1) : r * (q + 1) + (xcd - r) * q) + sub;
}

// ------------------- fused casts + rope tables + embedding -----------------
// One launch, block-range dispatch (r15-verified). Region layout:
//   [    0, 4608) cast_qkv      [ 4608, 6144) wob      [ 6144,15360) cast_gu
//   [15360,19968) wdnb          [19968,20736) cast6 R  [20736,20864) woutR
//   [20864,21632) cast6 W       [21632,21760) woutW    [21760,21824) embp
//   [21824,21952) rope          [21952,24000) embed (2 tokens/block; r22:
//                                             also emits bf16 Hbf copy)
struct CastArgs {
    const float *wq, *wk, *wv, *wob, *wg, *wu, *wdn;
    const float *r0, *r1, *r2, *r3, *r4, *r5, *woutR;
    const float *w0, *w1, *w2, *w3, *w4, *w5, *woutW;
    const float *emb; const int *ids;
    bf16 *wqkvD, *wobD, *wguD, *wdnbD, *wdRD, *woutRD, *wdWD, *woutWD, *embpD;
    float *cosT, *sinT, *H;
    bf16 *HbD;
};

__device__ __forceinline__ void cast4(const float* s, bf16* d, int i) {
    float4 v = ((const float4*)s)[i];
    BF4 u;
    u.h[0] = (bf16)v.x; u.h[1] = (bf16)v.y; u.h[2] = (bf16)v.z; u.h[3] = (bf16)v.w;
    ((short4*)d)[i] = u.p;
}

__global__ void cast_all(CastArgs a) {
    int bx = blockIdx.x, tid = threadIdx.x;
    if (bx < 4608) {                                   // qkv fuse
        int idx = bx * 256 + tid;
        int which = idx / 393216;
        int rem = idx - which * 393216;
        const float* s = which == 0 ? a.wq : which == 1 ? a.wk : a.wv;
        int layer = rem >> 16, rr = rem & 65535;
        int r = rr >> 7, c4 = rr & 127;
        float4 x = ((const float4*)s)[rem];
        BF4 u;
        u.h[0] = (bf16)x.x; u.h[1] = (bf16)x.y; u.h[2] = (bf16)x.z; u.h[3] = (bf16)x.w;
        ((short4*)a.wqkvD)[((size_t)layer * 1536 + which * 512 + r) * 128 + c4] = u.p;
    } else if (bx < 6144) {                            // wob plain
        cast4(a.wob, a.wobD, (bx - 4608) * 256 + tid);
    } else if (bx < 15360) {                           // gate/up interleave
        int idx = (bx - 6144) * 256 + tid;
        int which = idx / 1179648;
        int rem = idx - which * 1179648;
        const float* s = which == 0 ? a.wg : a.wu;
        int layer = rem / 196608, rr = rem - layer * 196608;
        int r = rr >> 7, c4 = rr & 127;
        float4 x = ((const float4*)s)[rem];
        BF4 u;
        u.h[0] = (bf16)x.x; u.h[1] = (bf16)x.y; u.h[2] = (bf16)x.z; u.h[3] = (bf16)x.w;
        ((short4*)a.wguD)[((size_t)layer * 3072 + r * 2 + which) * 128 + c4] = u.p;
    } else if (bx < 19968) {                           // wdnb plain
        cast4(a.wdn, a.wdnbD, (bx - 15360) * 256 + tid);
    } else if (bx < 20736) {                           // cast6 read-set
        int i = (bx - 19968) * 256 + tid;
        int which = i >> 15, loc = i & 32767;
        const float* s = which == 0 ? a.r0 : which == 1 ? a.r1 : which == 2 ? a.r2
                        : which == 3 ? a.r3 : which == 4 ? a.r4 : a.r5;
        cast4(s, a.wdRD + (size_t)which * 131072, loc);
    } else if (bx < 20864) {                           // woutR
        cast4(a.woutR, a.woutRD, (bx - 20736) * 256 + tid);
    } else if (bx < 21632) {                           // cast6 write-set
        int i = (bx - 20864) * 256 + tid;
        int which = i >> 15, loc = i & 32767;
        const float* s = which == 0 ? a.w0 : which == 1 ? a.w1 : which == 2 ? a.w2
                        : which == 3 ? a.w3 : which == 4 ? a.w4 : a.w5;
        cast4(s, a.wdWD + (size_t)which * 131072, loc);
    } else if (bx < 21760) {                           // woutW
        cast4(a.woutW, a.woutWD, (bx - 21632) * 256 + tid);
    } else if (bx < 21824) {                           // embed pad
        int i = (bx - 21760) * 256 + tid;
        int row = i >> 7, c4 = i & 127;
        BF4 u;
        if (row < VOCN) {
            float4 v = ((const float4*)a.emb)[row * 128 + c4];
            u.h[0] = (bf16)v.x; u.h[1] = (bf16)v.y; u.h[2] = (bf16)v.z; u.h[3] = (bf16)v.w;
        } else {
            u.h[0] = (bf16)0.f; u.h[1] = (bf16)0.f; u.h[2] = (bf16)0.f; u.h[3] = (bf16)0.f;
        }
        ((short4*)a.embpD)[i] = u.p;
    } else if (bx < 21952) {                           // rope tables
        int idx = (bx - 21824) * 256 + tid;
        int l = idx >> 5, d = idx & 31;
        double ang = (double)l * pow(500000.0, -(double)(2 * d) / 64.0);
        a.cosT[idx] = (float)cos(ang);
        a.sinT[idx] = (float)sin(ang);
    } else {                                           // embedding (2 tok/blk)
        int tok = (bx - 21952) * 2 + (tid >> 7);
        int id = a.ids[tok];
        float4 v = ((const float4*)(a.emb + (size_t)id * HIDDEN))[tid & 127];
        ((float4*)(a.H + (size_t)tok * HIDDEN))[tid & 127] = v;
        BF4 u;                                         // r22: bf16 copy for
        u.h[0] = (bf16)v.x; u.h[1] = (bf16)v.y;        // the delta-read proj
        u.h[2] = (bf16)v.z; u.h[3] = (bf16)v.w;        // (replaces cast_plain)
        ((short4*)(a.HbD + (size_t)tok * HIDDEN))[tid & 127] = u.p;
    }
}

// ------------------------------- rmsnorm -> bf16 ---------------------------
__global__ void rmsnorm512(const float* __restrict__ in, const float* __restrict__ w,
                           bf16* __restrict__ out) {
    int row = blockIdx.x, t = threadIdx.x;     // 128 threads
    float4 x = ((const float4*)(in + (size_t)row * 512))[t];
    float s = x.x * x.x + x.y * x.y + x.z * x.z + x.w * x.w;
    for (int m = 1; m < 64; m <<= 1) s += __shfl_xor(s, m);
    __shared__ float red[2];
    if ((t & 63) == 0) red[t >> 6] = s;
    __syncthreads();
    float tot = red[0] + red[1];
    float r = rsqrtf(tot * (1.f / 512.f) + 1e-6f);
    float4 wv = ((const float4*)w)[t];
    BF4 u;
    u.h[0] = (bf16)(x.x * r * wv.x); u.h[1] = (bf16)(x.y * r * wv.y);
    u.h[2] = (bf16)(x.z * r * wv.z); u.h[3] = (bf16)(x.w * r * wv.w);
    ((short4*)(out + (size_t)row * 512))[t] = u.p;
}

// ------------------------------- bf16 MFMA GEMM (128x128) ------------------
// C = A(bf16, MxK rm) @ B(bf16, NxK rm)^T. 128x128 tile, BK=64, 4 waves.
// LDS layout XOR-swizzled by 16B unit (pre-swizzled global source; r14).
// T1 XCD-aware block swizzle (r17). Single-buffered.
// MODE 0: C(f32)=v
// MODE 4: gate/up interleaved cols; Cb[row*Nreal+col/2]=bf16(silu(g)*u)
// MODE 5: fused QKV epilogue: RoPE(q,k)->Qb/Kb bf16 [bh][l][64]; V via
//         per-wave LDS transpose (r19) -> coalesced 16B Vtb stores.
template <int MODE>
__global__ __launch_bounds__(256) void gemm_bf16(const bf16* __restrict__ A,
                                                 const bf16* __restrict__ B,
                                                 float* __restrict__ C,
                                                 bf16* __restrict__ Cb,
                                                 const float* __restrict__ cosT,
                                                 const float* __restrict__ sinT,
                                                 bf16* __restrict__ Qb,
                                                 bf16* __restrict__ Kb,
                                                 bf16* __restrict__ Vtb,
                                                 int M, int N, int K, int Nreal) {
    __shared__ bf16 As[128 * 64];
    __shared__ bf16 Bs[128 * 64];
    const int tid = threadIdx.x;
    const int wave = tid >> 6, lane = tid & 63;
    const int nx = gridDim.x;
    const int wg = xcd_swz(blockIdx.y * nx + blockIdx.x, nx * gridDim.y);
    const int row0 = (wg / nx) * 128, col0 = (wg % nx) * 128;
    floatx4 acc[4][4];
#pragma unroll
    for (int i = 0; i < 4; ++i)
#pragma unroll
        for (int j = 0; j < 4; ++j) acc[i][j] = (floatx4){0.f, 0.f, 0.f, 0.f};
    const int m0 = (wave & 1) * 64, n0 = (wave >> 1) * 64;
    const int sr = tid >> 3;                       // 32 rows per staging call
    const int ske = ((tid & 7) ^ (sr & 7)) * 8;    // pre-swizzled k offset (elems)
    char* AsB = (char*)As;
    char* BsB = (char*)Bs;
    const int ldst = wave * 1024;
    const int ua0 = (((lane >> 4) + 0) ^ (lane & 7)) * 16;   // kk=0 unit byte
    const int ua1 = (((lane >> 4) + 4) ^ (lane & 7)) * 16;   // kk=1 unit byte

    for (int k0 = 0; k0 < K; k0 += 64) {
#pragma unroll
        for (int j = 0; j < 4; ++j) {
            gload16(A + (size_t)(row0 + j * 32 + sr) * K + ske + k0,
                    AsB + j * 4096 + ldst);
            gload16(B + (size_t)(col0 + j * 32 + sr) * K + ske + k0,
                    BsB + j * 4096 + ldst);
        }
        __syncthreads();
#pragma unroll
        for (int kk = 0; kk < 2; ++kk) {
            const int uu = kk ? ua1 : ua0;
            bf16x8 af[4], bfr[4];
#pragma unroll
            for (int mi = 0; mi < 4; ++mi)
                af[mi] = *(const bf16x8*)(AsB + (m0 + mi * 16 + (lane & 15)) * 128 + uu);
#pragma unroll
            for (int ni = 0; ni < 4; ++ni)
                bfr[ni] = *(const bf16x8*)(BsB + (n0 + ni * 16 + (lane & 15)) * 128 + uu);
#pragma unroll
            for (int mi = 0; mi < 4; ++mi)
#pragma unroll
                for (int ni = 0; ni < 4; ++ni)
                    acc[mi][ni] = __builtin_amdgcn_mfma_f32_16x16x32_bf16(af[mi], bfr[ni], acc[mi][ni], 0, 0, 0);
        }
        __syncthreads();
    }
    const int cr = (lane >> 4) * 4;
    const int cc = lane & 15;
    if (MODE == 5) {
        // wave-uniform 64-col span: segment + head fixed per wave
        int segbase = col0 + n0;
        int seg = segbase >> 9;           // 0=q 1=k 2=v
        int head = (segbase >> 6) & 7;
        if (seg < 2) {
#pragma unroll
            for (int mi = 0; mi < 4; ++mi) {
#pragma unroll
                for (int r = 0; r < 4; ++r) {
                    int row = row0 + m0 + mi * 16 + cr + r;
                    int b = row >> 10, l = row & 1023;
                    size_t bh = (size_t)(b * 8 + head);
                    float x0 = acc[mi][0][r], x1 = acc[mi][1][r];
                    float x2 = acc[mi][2][r], x3 = acc[mi][3][r];
                    float c0 = cosT[l * 32 + cc], c1 = cosT[l * 32 + 16 + cc];
                    float s0 = sinT[l * 32 + cc], s1 = sinT[l * 32 + 16 + cc];
                    bf16* dst = (seg == 0 ? Qb : Kb) + bh * 65536 + l * 64;
                    dst[cc]      = (bf16)(x0 * c0 - x2 * s0);
                    dst[16 + cc] = (bf16)(x1 * c1 - x3 * s1);
                    dst[32 + cc] = (bf16)(x2 * c0 + x0 * s0);
                    dst[48 + cc] = (bf16)(x3 * c1 + x1 * s1);
                }
            }
        } else {
            // r19: per-wave LDS transpose tile (8KB, As/Bs dead after K-loop).
            char* T = (wave < 2) ? ((char*)As + wave * 8192)
                                 : ((char*)Bs + (wave - 2) * 8192);
            int lb = row0 + m0;            // wave's token base (global row)
            int b = lb >> 10, l0 = lb & 1023;
            size_t bh = (size_t)(b * 8 + head);
            const int quad = lane >> 4;
            const int u = (quad >> 1);      // + mi*2 below
            const int h = (quad & 1) * 8;   // byte offset within unit
#pragma unroll
            for (int mi = 0; mi < 4; ++mi) {
#pragma unroll
                for (int ni = 0; ni < 4; ++ni) {
                    int d = ni * 16 + cc;
                    BF4 pk;
                    pk.h[0] = (bf16)acc[mi][ni][0];
                    pk.h[1] = (bf16)acc[mi][ni][1];
                    pk.h[2] = (bf16)acc[mi][ni][2];
                    pk.h[3] = (bf16)acc[mi][ni][3];
                    *(short4*)(T + d * 128 + ((mi * 2 + u) ^ (d & 7)) * 16 + h) = pk.p;
                }
            }
            int dl = lane >> 3, j = lane & 7;
#pragma unroll
            for (int i = 0; i < 8; ++i) {
                int d = i * 8 + dl;
                bf16x8 v = *(const bf16x8*)(T + d * 128 + ((j ^ dl) * 16));
                *(bf16x8*)(Vtb + bh * 65536 + (size_t)d * 1024 + l0 + j * 8) = v;
            }
        }
        return;
    }
#pragma unroll
    for (int mi = 0; mi < 4; ++mi) {
#pragma unroll
        for (int ni = 0; ni < 4; ++ni) {
#pragma unroll
            for (int r = 0; r < 4; ++r) {
                int row = row0 + m0 + mi * 16 + cr + r;
                int col = col0 + n0 + ni * 16 + cc;
                float v = acc[mi][ni][r];
                if (MODE == 4) {
                    float o = __shfl_xor(v, 1);
                    if (!(lane & 1)) {
                        float sg = v / (1.f + __expf(-v));
                        Cb[(size_t)row * Nreal + (col >> 1)] = (bf16)(sg * o);
                    }
                } else if (col < Nreal) {
                    size_t off = (size_t)row * Nreal + col;
                    if (MODE == 0) C[off] = v;
                }
            }
        }
    }
}

// ---------------------- 64x128-tile GEMM (accumulate) ----------------------
// Tile M=64, N=128, 4 waves each 32x64, BK=64, swizzled LDS (round 14).
// Round 16: LDS double-buffered (1 block/CU grids -> drains were exposed).
// Round 17: T1 XCD-aware block swizzle.
// MODE 0: C=v  MODE 1: C+=v  MODE 2: C+=v AND Cb=bf16(C_new) (r22: fuses
// the runtime H->Hbf cast into the last H-writing GEMM; bit-exact).
template <int MODE>
__global__ __launch_bounds__(256) void gemm64_bf16(const bf16* __restrict__ A,
                                                   const bf16* __restrict__ B,
                                                   float* __restrict__ C,
                                                   bf16* __restrict__ Cb,
                                                   int M, int N, int K, int Nreal) {
    __shared__ bf16 As[2][64 * 64];
    __shared__ bf16 Bs[2][128 * 64];
    const int tid = threadIdx.x;
    const int wave = tid >> 6, lane = tid & 63;
    const int nx = gridDim.x;
    const int wg = xcd_swz(blockIdx.y * nx + blockIdx.x, nx * gridDim.y);
    const int row0 = (wg / nx) * 64, col0 = (wg % nx) * 128;
    floatx4 acc[2][4];
#pragma unroll
    for (int i = 0; i < 2; ++i)
#pragma unroll
        for (int j = 0; j < 4; ++j) acc[i][j] = (floatx4){0.f, 0.f, 0.f, 0.f};
    const int m0 = (wave & 1) * 32, n0 = (wave >> 1) * 64;
    const int sr = tid >> 3;
    const int ske = ((tid & 7) ^ (sr & 7)) * 8;
    const int ldst = wave * 1024;
    const int ua0 = (((lane >> 4) + 0) ^ (lane & 7)) * 16;
    const int ua1 = (((lane >> 4) + 4) ^ (lane & 7)) * 16;

    auto stage = [&](int k0, int buf) {
        char* AsB = (char*)As[buf];
        char* BsB = (char*)Bs[buf];
#pragma unroll
        for (int j = 0; j < 2; ++j)
            gload16(A + (size_t)(row0 + j * 32 + sr) * K + ske + k0,
                    AsB + j * 4096 + ldst);
#pragma unroll
        for (int j = 0; j < 4; ++j)
            gload16(B + (size_t)(col0 + j * 32 + sr) * K + ske + k0,
                    BsB + j * 4096 + ldst);
    };

    const int nk = K >> 6;
    stage(0, 0);
    __syncthreads();
    int cur = 0;
    for (int t = 0; t < nk; ++t, cur ^= 1) {
        if (t + 1 < nk) stage((t + 1) * 64, cur ^ 1);
        const char* AsB = (const char*)As[cur];
        const char* BsB = (const char*)Bs[cur];
#pragma unroll
        for (int kk = 0; kk < 2; ++kk) {
            const int uu = kk ? ua1 : ua0;
            bf16x8 af[2], bfr[4];
#pragma unroll
            for (int mi = 0; mi < 2; ++mi)
                af[mi] = *(const bf16x8*)(AsB + (m0 + mi * 16 + (lane & 15)) * 128 + uu);
#pragma unroll
            for (int ni = 0; ni < 4; ++ni)
                bfr[ni] = *(const bf16x8*)(BsB + (n0 + ni * 16 + (lane & 15)) * 128 + uu);
#pragma unroll
            for (int mi = 0; mi < 2; ++mi)
#pragma unroll
                for (int ni = 0; ni < 4; ++ni)
                    acc[mi][ni] = __builtin_amdgcn_mfma_f32_16x16x32_bf16(af[mi], bfr[ni], acc[mi][ni], 0, 0, 0);
        }
        __syncthreads();
    }
    const int cr = (lane >> 4) * 4;
    const int cc = lane & 15;
#pragma unroll
    for (int mi = 0; mi < 2; ++mi) {
#pragma unroll
        for (int ni = 0; ni < 4; ++ni) {
#pragma unroll
            for (int r = 0; r < 4; ++r) {
                int row = row0 + m0 + mi * 16 + cr + r;
                int col = col0 + n0 + ni * 16 + cc;
                if (col < Nreal) {
                    size_t off = (size_t)row * Nreal + col;
                    float v = acc[mi][ni][r];
                    if (MODE == 0) {
                        C[off] = v;
                    } else {
                        float vn = C[off] + v;
                        C[off] = vn;
                        if (MODE == 2) Cb[off] = (bf16)vn;
                    }
                }
            }
        }
    }
}

// ------------------------- MFMA flash attention ----------------------------
// r20: causal load-balance — blocks with b&2 take qt' = 15-qt so each CU
// pair (same x,y; z differing by 2 = +256 block ids) processes qt + (15-qt)
// = 17 tiles instead of 2x the same qt (wall was 2x16). Bijective per-b.
// T5 setprio around MFMA clusters (2 blocks/CU -> waves at distinct phases).
__global__ __launch_bounds__(256) void attn_mfma(const bf16* __restrict__ Qb,
                                                 const bf16* __restrict__ Kb,
                                                 const bf16* __restrict__ Vtb,
                                                 bf16* __restrict__ O) {
    int qt = blockIdx.x, hh = blockIdx.y, b = blockIdx.z;
    if (b & 2) qt = gridDim.x - 1 - qt;    // complementary pairing
    int bh = b * 8 + hh;
    int q0 = qt * 64;
    const bf16* Qg = Qb + ((size_t)bh * 1024 + q0) * 64;
    const bf16* Kg = Kb + (size_t)bh * 1024 * 64;
    const bf16* Vg = Vtb + (size_t)bh * 64 * 1024;   // [64 d][1024 l]
    __shared__ bf16 Qs[64 * ATTS];
    __shared__ bf16 Ks[64 * ATTS];
    __shared__ bf16 Vs[64 * ATTS];
    __shared__ bf16 Ps[64 * ATTS];
    int tid = threadIdx.x, wave = tid >> 6, lane = tid & 63;
    int lr = lane & 15, quad = lane >> 4;

#pragma unroll
    for (int it = 0; it < 2; ++it) {
        int cidx = tid + it * 256;
        int row = cidx >> 3, ch = cidx & 7;
        *(bf16x8*)(Qs + row * ATTS + ch * 8) = *(const bf16x8*)(Qg + row * 64 + ch * 8);
    }
    float mrow[4], lrow[4];
    floatx4 Oacc[4];
#pragma unroll
    for (int r = 0; r < 4; ++r) { mrow[r] = -1e30f; lrow[r] = 0.f; }
#pragma unroll
    for (int d0 = 0; d0 < 4; ++d0) Oacc[d0] = (floatx4){0.f, 0.f, 0.f, 0.f};

    int ntiles = qt + 1;
    for (int t = 0; t < ntiles; ++t) {
        int kv0 = t * 64;
        __syncthreads();
#pragma unroll
        for (int it = 0; it < 2; ++it) {
            int cidx = tid + it * 256;
            int row = cidx >> 3, ch = cidx & 7;
            *(bf16x8*)(Ks + row * ATTS + ch * 8) =
                *(const bf16x8*)(Kg + (size_t)(kv0 + row) * 64 + ch * 8);
            *(bf16x8*)(Vs + row * ATTS + ch * 8) =
                *(const bf16x8*)(Vg + (size_t)row * 1024 + kv0 + ch * 8);
        }
        __syncthreads();
        bf16x8 aq[2];
#pragma unroll
        for (int kc = 0; kc < 2; ++kc)
            aq[kc] = *(const bf16x8*)(Qs + (wave * 16 + lr) * ATTS + kc * 32 + quad * 8);
        floatx4 sacc[4];
        __builtin_amdgcn_s_setprio(1);
#pragma unroll
        for (int n0 = 0; n0 < 4; ++n0) {
            bf16x8 bk0 = *(const bf16x8*)(Ks + (n0 * 16 + lr) * ATTS + quad * 8);
            bf16x8 bk1 = *(const bf16x8*)(Ks + (n0 * 16 + lr) * ATTS + 32 + quad * 8);
            floatx4 z = (floatx4){0.f, 0.f, 0.f, 0.f};
            z = __builtin_amdgcn_mfma_f32_16x16x32_bf16(aq[0], bk0, z, 0, 0, 0);
            sacc[n0] = __builtin_amdgcn_mfma_f32_16x16x32_bf16(aq[1], bk1, z, 0, 0, 0);
        }
        __builtin_amdgcn_s_setprio(0);
        float sv[4][4];
#pragma unroll
        for (int n0 = 0; n0 < 4; ++n0)
#pragma unroll
            for (int r = 0; r < 4; ++r) sv[n0][r] = sacc[n0][r] * 0.125f;
        if (t == ntiles - 1) {
#pragma unroll
            for (int n0 = 0; n0 < 4; ++n0)
#pragma unroll
                for (int r = 0; r < 4; ++r)
                    if (n0 * 16 + lr > wave * 16 + quad * 4 + r) sv[n0][r] = -1e30f;
        }
        float al[4];
#pragma unroll
        for (int r = 0; r < 4; ++r) {
            float tm = fmaxf(fmaxf(sv[0][r], sv[1][r]), fmaxf(sv[2][r], sv[3][r]));
            tm = fmaxf(tm, __shfl_xor(tm, 1));
            tm = fmaxf(tm, __shfl_xor(tm, 2));
            tm = fmaxf(tm, __shfl_xor(tm, 4));
            tm = fmaxf(tm, __shfl_xor(tm, 8));
            float mn = fmaxf(mrow[r], tm);
            al[r] = __expf(mrow[r] - mn);
            mrow[r] = mn;
        }
        float rs[4];
#pragma unroll
        for (int r = 0; r < 4; ++r) rs[r] = 0.f;
#pragma unroll
        for (int n0 = 0; n0 < 4; ++n0)
#pragma unroll
            for (int r = 0; r < 4; ++r) {
                float p = __expf(sv[n0][r] - mrow[r]);
                sv[n0][r] = p;
                rs[r] += p;
            }
#pragma unroll
        for (int r = 0; r < 4; ++r) {
            float t2 = rs[r];
            t2 += __shfl_xor(t2, 1);
            t2 += __shfl_xor(t2, 2);
            t2 += __shfl_xor(t2, 4);
            t2 += __shfl_xor(t2, 8);
            lrow[r] = lrow[r] * al[r] + t2;
        }
#pragma unroll
        for (int d0 = 0; d0 < 4; ++d0)
#pragma unroll
            for (int r = 0; r < 4; ++r) Oacc[d0][r] *= al[r];
#pragma unroll
        for (int n0 = 0; n0 < 4; ++n0)
#pragma unroll
            for (int r = 0; r < 4; ++r)
                Ps[(wave * 16 + quad * 4 + r) * ATTS + n0 * 16 + lr] = (bf16)sv[n0][r];
        bf16x8 ap[2];
#pragma unroll
        for (int kc = 0; kc < 2; ++kc)
            ap[kc] = *(const bf16x8*)(Ps + (wave * 16 + lr) * ATTS + kc * 32 + quad * 8);
        __builtin_amdgcn_s_setprio(1);
#pragma unroll
        for (int d0 = 0; d0 < 4; ++d0) {
            bf16x8 bv0 = *(const bf16x8*)(Vs + (d0 * 16 + lr) * ATTS + quad * 8);
            bf16x8 bv1 = *(const bf16x8*)(Vs + (d0 * 16 + lr) * ATTS + 32 + quad * 8);
            Oacc[d0] = __builtin_amdgcn_mfma_f32_16x16x32_bf16(ap[0], bv0, Oacc[d0], 0, 0, 0);
            Oacc[d0] = __builtin_amdgcn_mfma_f32_16x16x32_bf16(ap[1], bv1, Oacc[d0], 0, 0, 0);
        }
        __builtin_amdgcn_s_setprio(0);
    }
    float inv[4];
#pragma unroll
    for (int r = 0; r < 4; ++r) inv[r] = 1.f / lrow[r];
#pragma unroll
    for (int d0 = 0; d0 < 4; ++d0)
#pragma unroll
        for (int r = 0; r < 4; ++r) {
            int row = b * 1024 + q0 + wave * 16 + quad * 4 + r;
            int col = hh * 64 + d0 * 16 + lr;
            O[(size_t)row * 512 + col] = (bf16)(Oacc[d0][r] * inv[r]);
        }
}

// ------------------------------- delta scan --------------------------------
// Round 13 structure (verified, 95 us): 32 blocks x 512 threads. Waves 0-3
// (role 0) run the round-9 verified 2-token pair scan on chunk c; waves 4-7
// (role 1) stage chunk c+1 into the other LDS buffer. One barrier per chunk.
__global__ __launch_bounds__(512, 2) void delta_scan(
    const float* __restrict__ P, const float* __restrict__ S_in,
    const float* __restrict__ bbias, const float* __restrict__ abias,
    float* __restrict__ S_out, float* __restrict__ ctx) {
    int bh = blockIdx.x;
    int b = bh >> 3, hh = bh & 7;
    int tid = threadIdx.x;
    int role = tid >> 8;            // 0 = compute (waves 0-3), 1 = stage (4-7)
    int htid = tid & 255;
    int lane = htid & 63;
    int wv = htid >> 6;             // wave within role group
    int ri = wv * 8 + (lane >> 3);
    int c = lane & 7;
    bool cz = (c == 0);
    // double-buffered staging arrays (ks rows 64/65 = loadp pad)
    __shared__ __align__(16) float ks[2][66][36], qs[2][66][36], vs[2][66][36],
                                   bs[2][66][36], as_[2][66][36];
    __shared__ __align__(16) float cpair[2][33][4]; // [pair][c12,k1q1,k1q2,k2q2]
    __shared__ __align__(16) float cs[64][32];      // compute-only, single
    float4 S = *(const float4*)(S_in + ((size_t)bh * 32 + ri) * 32 + c * 4);

    int sc4 = htid & 7, sr0 = htid >> 3;   // staging map: token rows sr0, sr0+32
    float4 bB = *(const float4*)(bbias + hh * 32 + sc4 * 4);
    float4 bA = *(const float4*)(abias + hh * 32 + sc4 * 4);

    struct Pair {
        float4 k1, k2, q1, q2;
        float a1, a2, b1, b2, bv1, bv2;
        float c12, cq11, cq12, cq22;
    };

    auto dot4 = [](float4 s, float4 k) {
        return fmaf(s.w, k.w, fmaf(s.z, k.z, fmaf(s.y, k.y, s.x * k.x)));
    };

    // ---- stage one 64-token chunk into buffer `buf` (role-1 waves) ----
    auto stage_chunk = [&](int c0, int buf) {
        float (*ksH)[36] = ks[buf];
        float (*qsH)[36] = qs[buf];
        float (*vsH)[36] = vs[buf];
        float (*bsH)[36] = bs[buf];
        float (*asH)[36] = as_[buf];
        float (*cpH)[4]  = cpair[buf];
        const float* Pb = P + ((size_t)(b * 1024 + c0) * 1536) + hh * 32 + sc4 * 4;
#pragma unroll
        for (int it = 0; it < 2; ++it) {
            int tok = sr0 + it * 32;
            const float* pg = Pb + (size_t)tok * 1536;
            float4 kv = *(const float4*)(pg);
            float4 vv = *(const float4*)(pg + 256);
            float4 qv = *(const float4*)(pg + 512);
            float4 bv = *(const float4*)(pg + 768);
            float4 av = *(const float4*)(pg + 1024);
            float ss = kv.x * kv.x + kv.y * kv.y + kv.z * kv.z + kv.w * kv.w;
            ss = sum8(ss);
            float rn = 1.f / fmaxf(sqrtf(ss), 1e-12f);
            kv.x *= rn; kv.y *= rn; kv.z *= rn; kv.w *= rn;
            float4 bo, ao;
            bo.x = 1.f / (1.f + __expf(-(bv.x + bB.x)));
            bo.y = 1.f / (1.f + __expf(-(bv.y + bB.y)));
            bo.z = 1.f / (1.f + __expf(-(bv.z + bB.z)));
            bo.w = 1.f / (1.f + __expf(-(bv.w + bB.w)));
            ao.x = 1.f / (1.f + __expf(-(av.x + bA.x)));
            ao.y = 1.f / (1.f + __expf(-(av.y + bA.y)));
            ao.z = 1.f / (1.f + __expf(-(av.z + bA.z)));
            ao.w = 1.f / (1.f + __expf(-(av.w + bA.w)));
            float4 vo;
            vo.x = bo.x * vv.x; vo.y = bo.y * vv.y;
            vo.z = bo.z * vv.z; vo.w = bo.w * vv.w;
            // pair-shared dots: tokens 2j/2j+1 in adjacent 8-lane groups
            float kq = sum8(kv.x * qv.x + kv.y * qv.y + kv.z * qv.z + kv.w * qv.w);
            float4 ko, qo;
            ko.x = __shfl_xor(kv.x, 8); ko.y = __shfl_xor(kv.y, 8);
            ko.z = __shfl_xor(kv.z, 8); ko.w = __shfl_xor(kv.w, 8);
            qo.x = __shfl_xor(qv.x, 8); qo.y = __shfl_xor(qv.y, 8);
            qo.z = __shfl_xor(qv.z, 8); qo.w = __shfl_xor(qv.w, 8);
            float ckk = sum8(kv.x * ko.x + kv.y * ko.y + kv.z * ko.z + kv.w * ko.w);
            float ckq = sum8(kv.x * qo.x + kv.y * qo.y + kv.z * qo.z + kv.w * qo.w);
            *(float4*)&ksH[tok][sc4 * 4] = kv;
            *(float4*)&vsH[tok][sc4 * 4] = vo;
            *(float4*)&qsH[tok][sc4 * 4] = qv;
            *(float4*)&bsH[tok][sc4 * 4] = bo;
            *(float4*)&asH[tok][sc4 * 4] = ao;
            if ((htid & 7) == 0) {
                int pairi = tok >> 1;
                if (!(tok & 1)) {
                    cpH[pairi][0] = ckk;   // k1.k2
                    cpH[pairi][1] = kq;    // k1.q1
                    cpH[pairi][2] = ckq;   // k1.q2
                } else {
                    cpH[pairi][3] = kq;    // k2.q2
                }
            }
        }
    };

    // ---- scan one staged chunk from buffer `buf` (role-0 waves) ----
    auto scan_chunk = [&](int c0, int buf) {
        float (*ksH)[36] = ks[buf];
        float (*qsH)[36] = qs[buf];
        float (*vsH)[36] = vs[buf];
        float (*bsH)[36] = bs[buf];
        float (*asH)[36] = as_[buf];
        float (*cpH)[4]  = cpair[buf];
        auto loadp = [&](int t, Pair& Pr) {
            Pr.k1 = *(const float4*)&ksH[2 * t][c * 4];
            Pr.k2 = *(const float4*)&ksH[2 * t + 1][c * 4];
            Pr.q1 = *(const float4*)&qsH[2 * t][c * 4];
            Pr.q2 = *(const float4*)&qsH[2 * t + 1][c * 4];
            Pr.a1 = asH[2 * t][ri];  Pr.a2 = asH[2 * t + 1][ri];
            Pr.b1 = bsH[2 * t][ri];  Pr.b2 = bsH[2 * t + 1][ri];
            Pr.bv1 = vsH[2 * t][ri]; Pr.bv2 = vsH[2 * t + 1][ri];
            float4 cp = *(const float4*)&cpH[t][0];
            Pr.c12 = cp.x; Pr.cq11 = cp.y; Pr.cq12 = cp.z; Pr.cq22 = cp.w;
        };
        auto stepp = [&](const Pair& Pr, int t) {
            float d1  = sum8(dot4(S, Pr.k1));
            float d2  = sum8(dot4(S, Pr.k2));
            float dq1 = sum8(dot4(S, Pr.q1));
            float dq2 = sum8(dot4(S, Pr.q2));
            float u1 = fmaf(-(Pr.b1 * Pr.a1), d1, Pr.bv1);
            float au1 = Pr.a2 * u1;
            float A = Pr.a1 * Pr.a2;
            float pred2 = fmaf(au1, Pr.c12, A * d2);
            float u2 = fmaf(-Pr.b2, pred2, Pr.bv2);
            S.x = fmaf(u2, Pr.k2.x, fmaf(au1, Pr.k1.x, A * S.x));
            S.y = fmaf(u2, Pr.k2.y, fmaf(au1, Pr.k1.y, A * S.y));
            S.z = fmaf(u2, Pr.k2.z, fmaf(au1, Pr.k1.z, A * S.z));
            S.w = fmaf(u2, Pr.k2.w, fmaf(au1, Pr.k1.w, A * S.w));
            if (cz) {
                cs[2 * t][ri]     = fmaf(u1, Pr.cq11, Pr.a1 * dq1);
                cs[2 * t + 1][ri] = fmaf(u2, Pr.cq22, fmaf(au1, Pr.cq12, A * dq2));
            }
        };
        Pair PA, PB;
        loadp(0, PA);
        for (int t = 0; t < 32; t += 2) {
            loadp(t + 1, PB);
            stepp(PA, t);
            loadp(t + 2, PA);   // t==30 -> pair 32: pad rows 64/65, cpair[32]
            stepp(PB, t + 1);
        }
        // per-wave-own-rows ctx store: wave wv wrote cs[t][8wv..8wv+7]
        int gbase = b * 1024 + c0;
#pragma unroll
        for (int it = 0; it < 2; ++it) {
            int e = lane + it * 64;
            int t = e >> 1, j4 = wv * 2 + (e & 1);
            float4 val = *(const float4*)&cs[t][j4 * 4];
            *(float4*)(ctx + (size_t)(gbase + t) * 256 + hh * 32 + j4 * 4) = val;
        }
    };

    // ---- producer/consumer chunk pipeline ----
    if (role == 1) stage_chunk(0, 0);
    __syncthreads();
    for (int ch = 0; ch < 16; ++ch) {
        if (role == 1) {
            if (ch + 1 < 16) stage_chunk((ch + 1) * 64, (ch + 1) & 1);
        } else {
            scan_chunk(ch * 64, ch & 1);
        }
        __syncthreads();
    }
    if (role == 0)
        *(float4*)(S_out + ((size_t)bh * 32 + ri) * 32 + c * 4) = S;
}

// ------------- ctxbf = bf16(rmsnorm(ctx,nw)*silu(gate)), gate in P@1280 ----
__global__ void ctx_post(const float* __restrict__ ctx, const float* __restrict__ P,
                         const float* __restrict__ nw, bf16* __restrict__ out) {
    int row = blockIdx.x, t = threadIdx.x;  // 64 threads
    float4 x = ((const float4*)(ctx + (size_t)row * SDIMM))[t];
    float s = x.x * x.x + x.y * x.y + x.z * x.z + x.w * x.w;
    for (int m = 1; m < 64; m <<= 1) s += __shfl_xor(s, m);
    float r = rsqrtf(s * (1.f / 256.f) + 1e-6f);
    float4 n = ((const float4*)nw)[t];
    float4 g = ((const float4*)(P + (size_t)row * 1536 + 1280))[t];
    BF4 u;
    u.h[0] = (bf16)(x.x * r * n.x * (g.x / (1.f + __expf(-g.x))));
    u.h[1] = (bf16)(x.y * r * n.y * (g.y / (1.f + __expf(-g.y))));
    u.h[2] = (bf16)(x.z * r * n.z * (g.z / (1.f + __expf(-g.z))));
    u.h[3] = (bf16)(x.w * r * n.w * (g.w / (1.f + __expf(-g.w))));
    ((short4*)(out + (size_t)row * SDIMM))[t] = u.p;
}

// ---------------------------------------------------------------------------
extern "C" void kernel_launch(void* const* d_in, const int* in_sizes, int n_in,
                              void* d_out, int out_size, void* d_ws, size_t ws_size,
                              hipStream_t stream) {
    (void)in_sizes; (void)n_in; (void)out_size; (void)ws_size;
    const int* ids = (const int*)d_in[0];
    const float* state = (const float*)d_in[1];
    const float* embedw = (const float*)d_in[2];
    auto F = [&](int i) { return (const float*)d_in[i]; };

    char* wsb = (char*)d_ws;
    const size_t MB = 1048576;
    float* H    = (float*)(wsb);                 // 0-8 MB
    bf16*  XNbf = (bf16*)(wsb + 8 * MB);         // 8-12 (alias ctxf in delta)
    float* ctxf = (float*)(wsb + 8 * MB);
    bf16*  Hbf  = (bf16*)(wsb + 12 * MB);        // 12-16 (alias ctxb)
    bf16*  ctxb = (bf16*)(wsb + 12 * MB);
    float* P    = (float*)(wsb + 16 * MB);       // 16-40 (delta proj f32)
    bf16*  Obf  = (bf16*)(wsb + 40 * MB);        // 40-44 attn out
    bf16*  Qbuf = (bf16*)(wsb + 44 * MB);        // 44-48
    bf16*  Kbuf = (bf16*)(wsb + 48 * MB);        // 48-52
    bf16*  Vtb  = (bf16*)(wsb + 52 * MB);        // 52-56
    bf16*  A1b  = (bf16*)(wsb + 44 * MB);        // alias Q/K/Vt (dead after attn)
    float* cosT = (float*)(wsb + 58 * MB);
    float* sinT = cosT + 32768;
    float* Sbuf = sinT + 32768;
    char*  wbase = wsb + 59 * MB;
    bf16* wqkv  = (bf16*)(wbase);                        // 6x1536x512
    bf16* wob   = (bf16*)(wbase + 9437184);              // 6x512x512
    bf16* wgu   = (bf16*)(wbase + 12582912);             // 6x3072x512 interleaved
    bf16* wdnb  = (bf16*)(wbase + 31457280);             // 6x512x1536
    bf16* wdR   = (bf16*)(wbase + 40894464);             // 1536x512
    bf16* woutR = (bf16*)(wbase + 42467328);             // 512x256
    bf16* wdW   = (bf16*)(wbase + 42729472);             // 1536x512
    bf16* woutW = (bf16*)(wbase + 44302336);             // 512x256
    bf16* embp  = (bf16*)(wbase + 44564480);             // 128x512 padded

    float* out = (float*)d_out;
    float* logits = out;
    float* Sout = out + 4096 * VOCN;

    // 128x128-tile launches
    auto G0 = [&](const bf16* A, const bf16* B, float* C, int M, int N, int K, int Nreal) {
        gemm_bf16<0><<<dim3(N / 128, M / 128), 256, 0, stream>>>(
            A, B, C, nullptr, nullptr, nullptr, nullptr, nullptr, nullptr, M, N, K, Nreal);
    };
    auto G4 = [&](const bf16* A, const bf16* B, bf16* Cb, int M, int N, int K, int Nreal) {
        gemm_bf16<4><<<dim3(N / 128, M / 128), 256, 0, stream>>>(
            A, B, nullptr, Cb, nullptr, nullptr, nullptr, nullptr, nullptr, M, N, K, Nreal);
    };
    auto G5 = [&](const bf16* A, const bf16* B, int M, int N, int K) {
        gemm_bf16<5><<<dim3(N / 128, M / 128), 256, 0, stream>>>(
            A, B, nullptr, nullptr, cosT, sinT, Qbuf, Kbuf, Vtb, M, N, K, N);
    };
    // 64x128-tile accumulate
    auto G1s = [&](const bf16* A, const bf16* B, float* C, int M, int N, int K) {
        gemm64_bf16<1><<<dim3(N / 128, M / 64), 256, 0, stream>>>(A, B, C, nullptr,
                                                                  M, N, K, N);
    };
    auto G2s = [&](const bf16* A, const bf16* B, float* C, bf16* Cb, int M, int N, int K) {
        gemm64_bf16<2><<<dim3(N / 128, M / 64), 256, 0, stream>>>(A, B, C, Cb,
                                                                  M, N, K, N);
    };
    auto G0s = [&](const bf16* A, const bf16* B, float* C, int M, int N, int K, int Nreal) {
        gemm64_bf16<0><<<dim3(N / 128, M / 64), 256, 0, stream>>>(A, B, C, nullptr,
                                                                  M, N, K, Nreal);
    };

    // ---- fused weight casts + rope + embedding (+Hbf copy) in one launch ---
    CastArgs ca;
    ca.wq = F(24); ca.wk = F(25); ca.wv = F(26); ca.wob = F(27);
    ca.wg = F(29); ca.wu = F(30); ca.wdn = F(31);
    ca.r0 = F(3); ca.r1 = F(4); ca.r2 = F(5); ca.r3 = F(6); ca.r4 = F(8); ca.r5 = F(12);
    ca.woutR = F(10);
    ca.w0 = F(13); ca.w1 = F(14); ca.w2 = F(15); ca.w3 = F(16); ca.w4 = F(18); ca.w5 = F(22);
    ca.woutW = F(20);
    ca.emb = embedw; ca.ids = ids;
    ca.wqkvD = wqkv; ca.wobD = wob; ca.wguD = wgu; ca.wdnbD = wdnb;
    ca.wdRD = wdR; ca.woutRD = woutR; ca.wdWD = wdW; ca.woutWD = woutW;
    ca.embpD = embp; ca.cosT = cosT; ca.sinT = sinT; ca.H = H;
    ca.HbD = Hbf;
    cast_all<<<24000, 256, 0, stream>>>(ca);

    // ---- delta read (Hbf produced by cast_all embed region) ----
    G0(Hbf, wdR, P, 4096, 1536, 512, 1536);
    delta_scan<<<32, 512, 0, stream>>>(P, state, F(7), F(9), Sbuf, ctxf);
    ctx_post<<<4096, 64, 0, stream>>>(ctxf, P, F(11), ctxb);
    G1s(ctxb, woutR, H, 4096, 512, 256);

    for (int i = 0; i < 6; ++i) {
        rmsnorm512<<<4096, 128, 0, stream>>>(H, F(23) + (size_t)i * 512, XNbf);
        G5(XNbf, wqkv + (size_t)i * 1536 * 512, 4096, 1536, 512);
        attn_mfma<<<dim3(16, 8, 4), 256, 0, stream>>>(Qbuf, Kbuf, Vtb, Obf);
        G1s(Obf, wob + (size_t)i * 512 * 512, H, 4096, 512, 512);
        rmsnorm512<<<4096, 128, 0, stream>>>(H, F(28) + (size_t)i * 512, XNbf);
        G4(XNbf, wgu + (size_t)i * 3072 * 512, A1b, 4096, 3072, 512, 1536);
        if (i < 5) {
            G1s(A1b, wdnb + (size_t)i * 512 * 1536, H, 4096, 512, 1536);
        } else {
            // r22: last H writer also emits bf16 H for the delta-write proj
            G2s(A1b, wdnb + (size_t)i * 512 * 1536, H, Hbf, 4096, 512, 1536);
        }
    }

    // ---- delta write (Hbf produced by layer-5 down-proj epilogue) ----
    G0(Hbf, wdW, P, 4096, 1536, 512, 1536);
    delta_scan<<<32, 512, 0, stream>>>(P, Sbuf, F(17), F(19), Sout, ctxf);
    ctx_post<<<4096, 64, 0, stream>>>(ctxf, P, F(21), ctxb);
    G1s(ctxb, woutW, H, 4096, 512, 256);

    rmsnorm512<<<4096, 128, 0, stream>>>(H, F(32), XNbf);
    G0s(XNbf, embp, logits, 4096, 128, 512, VOCN);
}